// Round 12
// baseline (1135.275 us; speedup 1.0000x reference)
//
#include <hip/hip_runtime.h>

typedef unsigned short u16;
typedef unsigned int u32;
typedef __bf16 bf16x8 __attribute__((ext_vector_type(8)));
typedef float f32x4 __attribute__((ext_vector_type(4)));
typedef u16 u16x8 __attribute__((ext_vector_type(8)));
typedef u16 u16x4 __attribute__((ext_vector_type(4)));

static __device__ __forceinline__ u16 f2bf(float f) {
  u32 u = __builtin_bit_cast(u32, f);
  u32 r = (u + 0x7FFFu + ((u >> 16) & 1u)) >> 16;  // RNE; inputs finite
  return (u16)r;
}

static __device__ __forceinline__ void atomAddF32(float* p, float v) {
  asm volatile("global_atomic_add_f32 %0, %1, off" :: "v"(p), "v"(v) : "memory");
}

#define GLOAD_LDS16(gp, lp)                                                   \
  __builtin_amdgcn_global_load_lds(                                           \
      (const __attribute__((address_space(1))) void*)(gp),                    \
      (__attribute__((address_space(3))) void*)(lp), 16, 0, 0)

#define MFB(a, b, cc) __builtin_amdgcn_mfma_f32_16x16x32_bf16(a, b, cc, 0, 0, 0)

// ---------------- fused embedding + layer-0 LN1 ----------------
__global__ void k_embed_ln(const int* __restrict__ idx, const float* __restrict__ tok,
                           const float* __restrict__ pos, const float* __restrict__ sc,
                           const float* __restrict__ bi, float* __restrict__ x,
                           u16* __restrict__ out) {
  int row = blockIdx.x;            // b*1024 + t
  int tt = row & 1023;
  int id = idx[row];
  int t = threadIdx.x;
  float4 a = *(const float4*)(tok + (size_t)id * 1024 + t * 4);
  float4 p = *(const float4*)(pos + (size_t)tt * 1024 + t * 4);
  float4 v{a.x + p.x, a.y + p.y, a.z + p.z, a.w + p.w};
  *(float4*)(x + (size_t)row * 1024 + t * 4) = v;
  float s = v.x + v.y + v.z + v.w;
  float ss = v.x * v.x + v.y * v.y + v.z * v.z + v.w * v.w;
  for (int d = 1; d < 64; d <<= 1) { s += __shfl_xor(s, d); ss += __shfl_xor(ss, d); }
  __shared__ float red[8];
  int wave = t >> 6, lane = t & 63;
  if (lane == 0) { red[wave] = s; red[wave + 4] = ss; }
  __syncthreads();
  s = red[0] + red[1] + red[2] + red[3];
  ss = red[4] + red[5] + red[6] + red[7];
  float mu = s * (1.0f / 1024.0f);
  float var = ss * (1.0f / 1024.0f) - mu * mu;
  float inv = rsqrtf(var + 1e-5f);
  float4 g = *(const float4*)(sc + t * 4);
  float4 b = *(const float4*)(bi + t * 4);
  u16x4 o;
  o[0] = f2bf((v.x - mu) * inv * g.x + b.x);
  o[1] = f2bf((v.y - mu) * inv * g.y + b.y);
  o[2] = f2bf((v.z - mu) * inv * g.z + b.z);
  o[3] = f2bf((v.w - mu) * inv * g.w + b.w);
  *(u16x4*)(out + (size_t)row * 1024 + t * 4) = o;
}

// ---------------- layernorm (f32 in) -> bf16 out ----------------
__global__ void k_ln(const float* __restrict__ x, const float* __restrict__ sc,
                     const float* __restrict__ bi, u16* __restrict__ out) {
  int row = blockIdx.x;
  int t = threadIdx.x;
  const float* xr = x + (size_t)row * 1024;
  float4 v = *(const float4*)(xr + t * 4);
  float s = v.x + v.y + v.z + v.w;
  float ss = v.x * v.x + v.y * v.y + v.z * v.z + v.w * v.w;
  for (int d = 1; d < 64; d <<= 1) { s += __shfl_xor(s, d); ss += __shfl_xor(ss, d); }
  __shared__ float red[8];
  int wave = t >> 6, lane = t & 63;
  if (lane == 0) { red[wave] = s; red[wave + 4] = ss; }
  __syncthreads();
  s = red[0] + red[1] + red[2] + red[3];
  ss = red[4] + red[5] + red[6] + red[7];
  float mu = s * (1.0f / 1024.0f);
  float var = ss * (1.0f / 1024.0f) - mu * mu;
  float inv = rsqrtf(var + 1e-5f);
  float4 g = *(const float4*)(sc + t * 4);
  float4 b = *(const float4*)(bi + t * 4);
  u16x4 o;
  o[0] = f2bf((v.x - mu) * inv * g.x + b.x);
  o[1] = f2bf((v.y - mu) * inv * g.y + b.y);
  o[2] = f2bf((v.z - mu) * inv * g.z + b.z);
  o[3] = f2bf((v.w - mu) * inv * g.w + b.w);
  *(u16x4*)(out + (size_t)row * 1024 + t * 4) = o;
}

// ---------------- transpose+convert: f32 src[R][C] -> bf16 dst[C][R] ----------------
__launch_bounds__(1024)
__global__ void k_transpose(const float* __restrict__ src, u16* __restrict__ dst,
                            int R, int C) {
  __shared__ float tile[32][33];
  int tx = threadIdx.x, ty = threadIdx.y;
  int c = blockIdx.x * 32 + tx;
  int r = blockIdx.y * 32 + ty;
  tile[ty][tx] = src[(size_t)r * C + c];
  __syncthreads();
  int dr = blockIdx.x * 32 + ty;
  int dc = blockIdx.y * 32 + tx;
  dst[(size_t)dr * R + dc] = f2bf(tile[tx][ty]);
}

// ---------------- fused per-layer weight transpose (6 matrices, 1 launch) ----------
__launch_bounds__(1024)
__global__ void k_transpose_layer(const float* __restrict__ Wq, const float* __restrict__ Wk,
                                  const float* __restrict__ Wv, const float* __restrict__ Wo,
                                  const float* __restrict__ W1, const float* __restrict__ W2,
                                  u16* __restrict__ qkvT, u16* __restrict__ WoT,
                                  u16* __restrict__ W1T, u16* __restrict__ W2T) {
  int bid = blockIdx.x;
  const float* src; u16* dst; int R, C, bx, by;
  if (bid < 4096) {
    int which = bid >> 10, tile_i = bid & 1023;
    bx = tile_i & 31; by = tile_i >> 5; R = 1024; C = 1024;
    src = which == 0 ? Wq : which == 1 ? Wk : which == 2 ? Wv : Wo;
    dst = which == 3 ? WoT : qkvT + (size_t)which * 1048576;
  } else if (bid < 8192) {
    int tile_i = bid - 4096; bx = tile_i & 127; by = tile_i >> 7; R = 1024; C = 4096;
    src = W1; dst = W1T;
  } else {
    int tile_i = bid - 8192; bx = tile_i & 31; by = tile_i >> 5; R = 4096; C = 1024;
    src = W2; dst = W2T;
  }
  __shared__ float tile[32][33];
  int tx = threadIdx.x, ty = threadIdx.y;
  int c = bx * 32 + tx, r = by * 32 + ty;
  tile[ty][tx] = src[(size_t)r * C + c];
  __syncthreads();
  int dr = bx * 32 + ty, dc = by * 32 + tx;
  dst[(size_t)dr * R + dc] = f2bf(tile[tx][ty]);
}

// ---------------- GEMMs: C[M][N] = A[M][K](bf16) x Bt[N][K](bf16)^T ----------------
enum { EPI_QKV = 0, EPI_RELU = 2 };

// 64x128 tile, 2-phase pipelined (QKV / RELU). LDS-staged coalesced epilogues.
template <int EPI>
__launch_bounds__(256, 4)
__global__ void k_gemm64(const u16* __restrict__ A, const u16* __restrict__ Bt,
                         const float* __restrict__ bias, u16* __restrict__ bout,
                         int M, int N, int K) {
  __shared__ alignas(16) u16 smem[12288];   // Al[2][64][32] | Bl[2][128][32]
#define AL(s, r, k) smem[(s)*2048 + (r)*32 + (k)]
#define BL(s, r, k) smem[4096 + (s)*4096 + (r)*32 + (k)]
  const int t = threadIdx.x;
  const int wave = t >> 6, lane = t & 63;
  const int wm = wave >> 1, wn = wave & 1;       // 2x2 waves: 32x64 out each
  const int g = lane >> 4, c = lane & 15;
  const int m0 = blockIdx.x * 64, n0 = blockIdx.y * 128;

  const int rwA = t >> 2, sgA = (t & 3) * 8;
  const u16* gA = A + (size_t)(m0 + rwA) * K + sgA;
  const u16* gB = Bt + (size_t)(n0 + rwA) * K + sgA;

  f32x4 acc[2][4] = {};
  const int nK = K >> 5;
  int cur = 0;

  GLOAD_LDS16(gA, &AL(0, rwA, 0));
#pragma unroll
  for (int p = 0; p < 2; ++p)
    GLOAD_LDS16(gB + (size_t)p * 64 * K, &BL(0, p * 64 + rwA, 0));
  __syncthreads();

  for (int kt = 0; kt < nK; ++kt) {
    if (kt + 1 < nK) {
      const int k0 = (kt + 1) << 5;
      GLOAD_LDS16(gA + k0, &AL(cur ^ 1, rwA, 0));
#pragma unroll
      for (int p = 0; p < 2; ++p)
        GLOAD_LDS16(gB + k0 + (size_t)p * 64 * K, &BL(cur ^ 1, p * 64 + rwA, 0));
    }
    bf16x8 af[2], bfr[4];
#pragma unroll
    for (int i = 0; i < 2; ++i)
      af[i] = *(const bf16x8*)&AL(cur, wm * 32 + i * 16 + c, g * 8);
#pragma unroll
    for (int j = 0; j < 4; ++j)
      bfr[j] = *(const bf16x8*)&BL(cur, wn * 64 + j * 16 + c, g * 8);
#pragma unroll
    for (int i = 0; i < 2; ++i)
#pragma unroll
      for (int j = 0; j < 4; ++j)
        acc[i][j] = MFB(af[i], bfr[j], acc[i][j]);
    __syncthreads();
    cur ^= 1;
  }

  if (EPI == EPI_QKV) {
    const int which = n0 >> 10;                  // 0=Q 1=K 2=V (uniform per block)
    const int b = m0 >> 10, t0 = m0 & 1023;
    const int hh0 = (n0 >> 6) & 15;
    if (which < 2) {
      const float qsc = (which == 0) ? 0.125f : 1.0f;   // pre-scale Q by 1/sqrt(HD)
      u16 (*Ct)[136] = (u16(*)[136])smem;
#pragma unroll
      for (int i = 0; i < 2; ++i)
#pragma unroll
        for (int j = 0; j < 4; ++j)
#pragma unroll
          for (int r = 0; r < 4; ++r)
            Ct[wm * 32 + i * 16 + g * 4 + r][wn * 64 + j * 16 + c] = f2bf(acc[i][j][r] * qsc);
      __syncthreads();
      u16* obase = bout + (size_t)which * 2097152;
#pragma unroll
      for (int itr = 0; itr < 4; ++itr) {
        int idx2 = itr * 256 + t;
        int s = idx2 >> 9;
        int tt = (idx2 >> 3) & 63;
        int seg = idx2 & 7;
        u16x8 vv = *(const u16x8*)&Ct[tt][s * 64 + seg * 8];
        *(u16x8*)(obase + ((size_t)(b * 16 + hh0 + s) * 1024 + (t0 + tt)) * 64 + seg * 8) = vv;
      }
    } else {
      // V transposed: stage [128 feat][72 tok], store [bh][d][t]
      u16 (*Cv)[72] = (u16(*)[72])smem;
#pragma unroll
      for (int i = 0; i < 2; ++i)
#pragma unroll
        for (int j = 0; j < 4; ++j) {
          u16x4 pk;
#pragma unroll
          for (int r = 0; r < 4; ++r) pk[r] = f2bf(acc[i][j][r]);
          *(u16x4*)&Cv[wn * 64 + j * 16 + c][wm * 32 + i * 16 + g * 4] = pk;
        }
      __syncthreads();
      u16* obase = bout + (size_t)2 * 2097152;
#pragma unroll
      for (int itr = 0; itr < 4; ++itr) {
        int idx2 = itr * 256 + t;
        int row = idx2 >> 3;
        int seg = idx2 & 7;
        int s = row >> 6, f = row & 63;
        u16x8 vv = *(const u16x8*)&Cv[row][seg * 8];
        *(u16x8*)(obase + ((size_t)(b * 16 + hh0 + s) * 64 + f) * 1024 + t0 + seg * 8) = vv;
      }
    }
  } else {  // EPI_RELU
    u16 (*Ct)[136] = (u16(*)[136])smem;
#pragma unroll
    for (int i = 0; i < 2; ++i)
#pragma unroll
      for (int j = 0; j < 4; ++j)
#pragma unroll
        for (int r = 0; r < 4; ++r) {
          float u = acc[i][j][r] + bias[n0 + wn * 64 + j * 16 + c];
          Ct[wm * 32 + i * 16 + g * 4 + r][wn * 64 + j * 16 + c] = f2bf(u > 0.f ? u : 0.f);
        }
    __syncthreads();
#pragma unroll
    for (int itr = 0; itr < 4; ++itr) {
      int idx2 = itr * 256 + t;
      int tt = idx2 >> 4, seg = idx2 & 15;
      *(u16x8*)(bout + (size_t)(m0 + tt) * N + n0 + seg * 8) =
          *(const u16x8*)&Ct[tt][seg * 8];
    }
  }
#undef AL
#undef BL
}

// 64x64 tile, 2-phase, SPLIT-K over gridDim.z; residual += via HW f32 atomics
__launch_bounds__(256, 8)
__global__ void k_gemm_res(const u16* __restrict__ A, const u16* __restrict__ Bt,
                           const float* __restrict__ bias, float* __restrict__ fout,
                           int M, int N, int K) {
  __shared__ alignas(16) u16 smem[8192];   // Al[2][64][32] | Bl[2][64][32]
  const int t = threadIdx.x;
  const int wave = t >> 6, lane = t & 63;
  const int wm = wave >> 1, wn = wave & 1;   // 2x2 waves: 32x32 out each
  const int g = lane >> 4, c = lane & 15;
  const int m0 = blockIdx.x * 64, n0 = blockIdx.y * 64;
  const int kz = blockIdx.z;
  const int Kh = K / gridDim.z;              // per-split K
  const int kbase = kz * Kh;

  const int rw = t >> 2, sg = (t & 3) * 8;
  const u16* gA = A + (size_t)(m0 + rw) * K + kbase + sg;
  const u16* gB = Bt + (size_t)(n0 + rw) * K + kbase + sg;

  f32x4 acc[2][2] = {};
  const int nK = Kh >> 5;
  int cur = 0;

  GLOAD_LDS16(gA, &smem[rw * 32]);
  GLOAD_LDS16(gB, &smem[4096 + rw * 32]);
  __syncthreads();

  for (int kt = 0; kt < nK; ++kt) {
    if (kt + 1 < nK) {
      const int k0 = (kt + 1) << 5;
      GLOAD_LDS16(gA + k0, &smem[(cur ^ 1) * 2048 + rw * 32]);
      GLOAD_LDS16(gB + k0, &smem[4096 + (cur ^ 1) * 2048 + rw * 32]);
    }
    bf16x8 af[2], bfr[2];
#pragma unroll
    for (int i = 0; i < 2; ++i)
      af[i] = *(const bf16x8*)&smem[cur * 2048 + (wm * 32 + i * 16 + c) * 32 + g * 8];
#pragma unroll
    for (int j = 0; j < 2; ++j)
      bfr[j] = *(const bf16x8*)&smem[4096 + cur * 2048 + (wn * 32 + j * 16 + c) * 32 + g * 8];
#pragma unroll
    for (int i = 0; i < 2; ++i)
#pragma unroll
      for (int j = 0; j < 2; ++j)
        acc[i][j] = MFB(af[i], bfr[j], acc[i][j]);
    __syncthreads();
    cur ^= 1;
  }

#pragma unroll
  for (int i = 0; i < 2; ++i)
#pragma unroll
    for (int j = 0; j < 2; ++j)
#pragma unroll
      for (int r = 0; r < 4; ++r) {
        int m = m0 + wm * 32 + i * 16 + g * 4 + r;
        int n = n0 + wn * 32 + j * 16 + c;
        float v = acc[i][j][r] + (kz == 0 ? bias[n] : 0.f);
        atomAddF32(&fout[(size_t)m * N + n], v);
      }
}

// ---------------- GEMM 128x128 2-phase (LM head, f32+bias out), XCD swizzle ------
__launch_bounds__(256, 4)
__global__ void k_gemm_out(const u16* __restrict__ A, const u16* __restrict__ Bt,
                           const float* __restrict__ bias, float* __restrict__ fout,
                           int M, int N, int K) {
  __shared__ alignas(16) u16 sm[2][2][128][32];
  const int t = threadIdx.x;
  const int wave = t >> 6, lane = t & 63;
  const int wm = wave >> 1, wn = wave & 1;
  const int g = lane >> 4, c = lane & 15;
  // 4000 blocks = 8 XCDs x 500: bijective chunked swizzle; M fast within chunk
  const int wg = (blockIdx.x & 7) * 500 + (blockIdx.x >> 3);
  const int m0 = (wg & 15) * 128, n0 = (wg >> 4) * 128;

  const int srow = wave * 32 + (lane >> 2);
  const int sseg = (lane & 3) * 8;
  const u16* gA = A + (size_t)(m0 + srow) * K + sseg;
  const u16* gB = Bt + (size_t)(n0 + srow) * K + sseg;

  f32x4 acc[4][4] = {};
  const int nK = K >> 5;
  int cur = 0;

#pragma unroll
  for (int p = 0; p < 2; ++p) {
    GLOAD_LDS16(gA + (size_t)p * 16 * K, &sm[0][0][wave * 32 + p * 16][0]);
    GLOAD_LDS16(gB + (size_t)p * 16 * K, &sm[0][1][wave * 32 + p * 16][0]);
  }
  __syncthreads();

  for (int kt = 0; kt < nK; ++kt) {
    if (kt + 1 < nK) {
      const int k0 = (kt + 1) << 5;
#pragma unroll
      for (int p = 0; p < 2; ++p) {
        GLOAD_LDS16(gA + k0 + (size_t)p * 16 * K, &sm[cur ^ 1][0][wave * 32 + p * 16][0]);
        GLOAD_LDS16(gB + k0 + (size_t)p * 16 * K, &sm[cur ^ 1][1][wave * 32 + p * 16][0]);
      }
    }
    bf16x8 af[4], bfr[4];
#pragma unroll
    for (int i = 0; i < 4; ++i) {
      af[i]  = *(const bf16x8*)&sm[cur][0][wm * 64 + i * 16 + c][g * 8];
      bfr[i] = *(const bf16x8*)&sm[cur][1][wn * 64 + i * 16 + c][g * 8];
    }
#pragma unroll
    for (int i = 0; i < 4; ++i)
#pragma unroll
      for (int j = 0; j < 4; ++j)
        acc[i][j] = MFB(af[i], bfr[j], acc[i][j]);
    __syncthreads();
    cur ^= 1;
  }

  float (*st)[132] = (float(*)[132])sm;
#pragma unroll
  for (int i = 0; i < 4; ++i) {
#pragma unroll
    for (int j = 0; j < 4; ++j)
#pragma unroll
      for (int r = 0; r < 4; ++r)
        st[wm * 16 + g * 4 + r][wn * 64 + j * 16 + c] = acc[i][j][r];
    __syncthreads();
    {
      int row = t >> 3;
      int cs = (t & 7) * 16;
      int m = m0 + (row >> 4) * 64 + i * 16 + (row & 15);
      float* dst = fout + (size_t)m * N + n0 + cs;
#pragma unroll
      for (int q = 0; q < 4; ++q) {
        float4 v = *(const float4*)&st[row][cs + q * 4];
        float4 bb = *(const float4*)&bias[n0 + cs + q * 4];
        float4 o{v.x + bb.x, v.y + bb.y, v.z + bb.z, v.w + bb.w};
        *(float4*)(dst + q * 4) = o;
      }
    }
    __syncthreads();
  }
}

// ---------------- flash attention: 4-way K-split + tree merge ----------------
// Q pre-scaled by 1/8; mask only diagonal tile; per-lane deferred L-reduction.
#define AITER(ITV, MASKED)                                                    \
  {                                                                           \
    const int k0 = (ITV) << 5;                                                \
    bf16x8 kb0 = *(const bf16x8*)(Kh + (k0 + c) * 64 + g * 8);                \
    bf16x8 kb1 = *(const bf16x8*)(Kh + (k0 + c) * 64 + 32 + g * 8);           \
    bf16x8 kb2 = *(const bf16x8*)(Kh + (k0 + 16 + c) * 64 + g * 8);           \
    bf16x8 kb3 = *(const bf16x8*)(Kh + (k0 + 16 + c) * 64 + 32 + g * 8);      \
    bf16x8 bv0 = *(const bf16x8*)(VTh + (size_t)(c) * 1024 + k0 + g * 8);     \
    bf16x8 bv1 = *(const bf16x8*)(VTh + (size_t)(16 + c) * 1024 + k0 + g * 8);\
    bf16x8 bv2 = *(const bf16x8*)(VTh + (size_t)(32 + c) * 1024 + k0 + g * 8);\
    bf16x8 bv3 = *(const bf16x8*)(VTh + (size_t)(48 + c) * 1024 + k0 + g * 8);\
    f32x4 S[2][2];                                                            \
    __builtin_amdgcn_s_setprio(1);                                            \
    _Pragma("unroll") for (int qt = 0; qt < 2; ++qt) {                        \
      f32x4 z = {};                                                           \
      S[qt][0] = MFB(aq[qt][1], kb1, MFB(aq[qt][0], kb0, z));                 \
      S[qt][1] = MFB(aq[qt][1], kb3, MFB(aq[qt][0], kb2, z));                 \
    }                                                                         \
    __builtin_amdgcn_s_setprio(0);                                            \
    float sv[2][2][4], mt[2][4];                                              \
    float need = 0.0f;                                                        \
    _Pragma("unroll") for (int qt = 0; qt < 2; ++qt)                          \
      _Pragma("unroll") for (int r = 0; r < 4; ++r) {                         \
        float s0 = S[qt][0][r], s1 = S[qt][1][r];                             \
        if (MASKED) {                                                         \
          int q = q0 + qt * 16 + (g << 2) + r;                                \
          s0 = (k0 + c <= q) ? s0 : -1e30f;                                   \
          s1 = (k0 + 16 + c <= q) ? s1 : -1e30f;                              \
        }                                                                     \
        sv[qt][0][r] = s0; sv[qt][1][r] = s1;                                 \
        float m = fmaxf(s0, s1);                                              \
        m = fmaxf(m, __shfl_xor(m, 1));                                       \
        m = fmaxf(m, __shfl_xor(m, 2));                                       \
        m = fmaxf(m, __shfl_xor(m, 4));                                       \
        m = fmaxf(m, __shfl_xor(m, 8));                                       \
        mt[qt][r] = m;                                                        \
        need = fmaxf(need, m - Mr[qt][r]);                                    \
      }                                                                       \
    const bool nore = __all(need <= 8.0f);                                    \
    _Pragma("unroll") for (int qt = 0; qt < 2; ++qt)                          \
      _Pragma("unroll") for (int r = 0; r < 4; ++r) {                         \
        float mn = nore ? Mr[qt][r] : fmaxf(Mr[qt][r], mt[qt][r]);            \
        float p0 = __expf(sv[qt][0][r] - mn);                                 \
        float p1 = __expf(sv[qt][1][r] - mn);                                 \
        if (nore) {                                                           \
          Lr[qt][r] += p0 + p1;       /* per-lane partial; reduced at end */  \
        } else {                                                              \
          float alpha = __expf(Mr[qt][r] - mn);                               \
          Lr[qt][r] = Lr[qt][r] * alpha + p0 + p1;                            \
          Mr[qt][r] = mn;                                                     \
          _Pragma("unroll") for (int nb = 0; nb < 4; ++nb) Oacc[qt][nb][r] *= alpha; \
        }                                                                     \
        Pl[wv][qt * 16 + (g << 2) + r][c] = f2bf(p0);                         \
        Pl[wv][qt * 16 + (g << 2) + r][16 + c] = f2bf(p1);                    \
      }                                                                       \
    __builtin_amdgcn_s_setprio(1);                                            \
    _Pragma("unroll") for (int qt = 0; qt < 2; ++qt) {                        \
      bf16x8 ap = *(const bf16x8*)&Pl[wv][qt * 16 + c][g * 8];                \
      Oacc[qt][0] = MFB(ap, bv0, Oacc[qt][0]);                                \
      Oacc[qt][1] = MFB(ap, bv1, Oacc[qt][1]);                                \
      Oacc[qt][2] = MFB(ap, bv2, Oacc[qt][2]);                                \
      Oacc[qt][3] = MFB(ap, bv3, Oacc[qt][3]);                                \
    }                                                                         \
    __builtin_amdgcn_s_setprio(0);                                            \
  }

#define PUBLISH(slot)                                                         \
  {                                                                           \
    _Pragma("unroll") for (int qt = 0; qt < 2; ++qt) {                        \
      _Pragma("unroll") for (int nb = 0; nb < 4; ++nb)                        \
        _Pragma("unroll") for (int r = 0; r < 4; ++r)                         \
          pub[slot][lane][qt * 16 + nb * 4 + r] = Oacc[qt][nb][r];            \
      _Pragma("unroll") for (int r = 0; r < 4; ++r) {                         \
        pub[slot][lane][32 + qt * 4 + r] = Mr[qt][r];                         \
        pub[slot][lane][40 + qt * 4 + r] = Lr[qt][r];                         \
      }                                                                       \
    }                                                                         \
  }

#define MERGEIN(slot)                                                         \
  {                                                                           \
    _Pragma("unroll") for (int qt = 0; qt < 2; ++qt)                          \
      _Pragma("unroll") for (int r = 0; r < 4; ++r) {                         \
        float m1 = pub[slot][lane][32 + qt * 4 + r];                          \
        float l1 = pub[slot][lane][40 + qt * 4 + r];                          \
        float mm = fmaxf(Mr[qt][r], m1);                                      \
        float a0 = __expf(Mr[qt][r] - mm);                                    \
        float a1 = __expf(m1 - mm);                                           \
        Lr[qt][r] = a0 * Lr[qt][r] + a1 * l1;                                 \
        Mr[qt][r] = mm;                                                       \
        _Pragma("unroll") for (int nb = 0; nb < 4; ++nb)                      \
          Oacc[qt][nb][r] = a0 * Oacc[qt][nb][r] +                            \
                            a1 * pub[slot][lane][qt * 16 + nb * 4 + r];       \
      }                                                                       \
  }

__launch_bounds__(256)
__global__ void k_attn(const u16* __restrict__ Q, const u16* __restrict__ Kb,
                       const u16* __restrict__ VT, u16* __restrict__ O) {
  const int qb = 31 - blockIdx.x;  // heavy blocks dispatch first
  const int bh = blockIdx.y;       // 0..31
  const int tid = threadIdx.x;
  const int wv = tid >> 6;         // wave 0..3: K quarter
  const int lane = tid & 63;
  const int g = lane >> 4, c = lane & 15;
  const int q0 = qb << 5;
  const u16* Qh = Q + (size_t)bh * 65536;
  const u16* Kh = Kb + (size_t)bh * 65536;
  const u16* VTh = VT + (size_t)bh * 65536;

  __shared__ u16 Pl[4][32][40];
  __shared__ float pub[2][64][48];

  bf16x8 aq[2][2];
#pragma unroll
  for (int qt = 0; qt < 2; ++qt) {
    aq[qt][0] = *(const bf16x8*)(Qh + (q0 + qt * 16 + c) * 64 + g * 8);
    aq[qt][1] = *(const bf16x8*)(Qh + (q0 + qt * 16 + c) * 64 + 32 + g * 8);
  }

  f32x4 Oacc[2][4] = {};
  float Mr[2][4], Lr[2][4] = {};
#pragma unroll
  for (int qt = 0; qt < 2; ++qt)
#pragma unroll
    for (int r = 0; r < 4; ++r) Mr[qt][r] = -1e30f;

  const int nIt = qb + 1;
  const int q4 = (nIt + 3) >> 2;
  const int beg = wv * q4;
  const int end = min(nIt, beg + q4);
  const int endU = min(end, nIt - 1);
  for (int it = beg; it < endU; ++it) AITER(it, 0);   // interior: unmasked
  if (beg < nIt && end == nIt) AITER(nIt - 1, 1);     // owner of diagonal tile

  // tree merge: (1,3) publish -> (0,2) merge; 2 publishes -> 0 merges + writes
  if (wv == 1) PUBLISH(0);
  if (wv == 3) PUBLISH(1);
  __syncthreads();
  if (wv == 0) MERGEIN(0);
  if (wv == 2) MERGEIN(1);
  __syncthreads();
  if (wv == 2) PUBLISH(0);
  __syncthreads();
  if (wv == 0) {
    MERGEIN(0);
    const int b = bh >> 4, hh = bh & 15;
#pragma unroll
    for (int qt = 0; qt < 2; ++qt)
#pragma unroll
      for (int r = 0; r < 4; ++r) {
        float l = Lr[qt][r];               // per-lane partial
        l += __shfl_xor(l, 1);
        l += __shfl_xor(l, 2);
        l += __shfl_xor(l, 4);
        l += __shfl_xor(l, 8);
        float invl = 1.0f / l;
        int tt = q0 + qt * 16 + (g << 2) + r;
#pragma unroll
        for (int nb = 0; nb < 4; ++nb) {
          int d = nb * 16 + c;
          O[((size_t)(b * 1024 + tt)) * 1024 + hh * 64 + d] = f2bf(Oacc[qt][nb][r] * invl);
        }
      }
  }
}

// ---------------- launch ----------------
extern "C" void kernel_launch(void* const* d_in, const int* in_sizes, int n_in,
                              void* d_out, int out_size, void* d_ws, size_t ws_size,
                              hipStream_t stream) {
  const int*   idx  = (const int*)d_in[0];
  const float* tok  = (const float*)d_in[1];
  const float* pos  = (const float*)d_in[2];
  const float* Wq   = (const float*)d_in[3];
  const float* Wk   = (const float*)d_in[4];
  const float* Wv   = (const float*)d_in[5];
  const float* Wo   = (const float*)d_in[6];
  const float* bo   = (const float*)d_in[7];
  const float* ln1s = (const float*)d_in[8];
  const float* ln1b = (const float*)d_in[9];
  const float* ln2s = (const float*)d_in[10];
  const float* ln2b = (const float*)d_in[11];
  const float* W1   = (const float*)d_in[12];
  const float* b1   = (const float*)d_in[13];
  const float* W2   = (const float*)d_in[14];
  const float* b2   = (const float*)d_in[15];
  const float* lnfs = (const float*)d_in[16];
  const float* lnfb = (const float*)d_in[17];
  const float* Wlm  = (const float*)d_in[18];
  const float* blm  = (const float*)d_in[19];
  float* out = (float*)d_out;

  char* w = (char*)d_ws;
  auto alloc = [&](size_t bytes) {
    char* p = w;
    w += (bytes + 255) & ~(size_t)255;
    return p;
  };
  float* x  = (float*)alloc(2048ull * 1024 * 4);
  u16* h    = (u16*)alloc(2048ull * 1024 * 2);
  u16* qkv  = (u16*)alloc(3ull * 2097152 * 2);   // Q,K: [bh][t][64]; V: [bh][d][t]
  u16* o    = (u16*)alloc(2048ull * 1024 * 2);
  u16* a1   = (u16*)alloc(2048ull * 4096 * 2);
  u16* arena = (u16*)alloc(32000ull * 1024 * 2);

  dim3 b32(32, 32, 1);

  k_embed_ln<<<2048, 256, 0, stream>>>(idx, tok, pos, ln1s, ln1b, x, h);

  for (int l = 0; l < 4; ++l) {
    u16* qkvT = arena;
    u16* WoT  = arena + 3ull * 1048576;
    u16* W1T  = arena + 4ull * 1048576;
    u16* W2T  = arena + 8ull * 1048576;
    k_transpose_layer<<<12288, b32, 0, stream>>>(
        Wq + (size_t)l * 1048576, Wk + (size_t)l * 1048576,
        Wv + (size_t)l * 1048576, Wo + (size_t)l * 1048576,
        W1 + (size_t)l * 4194304, W2 + (size_t)l * 4194304,
        qkvT, WoT, W1T, W2T);

    if (l > 0)
      k_ln<<<2048, 256, 0, stream>>>(x, ln1s + l * 1024, ln1b + l * 1024, h);
    k_gemm64<EPI_QKV><<<dim3(32, 24), 256, 0, stream>>>(h, qkvT, nullptr, qkv,
                                                        2048, 3072, 1024);
    k_attn<<<dim3(32, 32), 256, 0, stream>>>(qkv, qkv + 2097152, qkv + 2 * 2097152, o);
    k_gemm_res<<<dim3(32, 16, 2), 256, 0, stream>>>(o, WoT, bo + l * 1024, x,
                                                    2048, 1024, 1024);
    k_ln<<<2048, 256, 0, stream>>>(x, ln2s + l * 1024, ln2b + l * 1024, h);
    k_gemm64<EPI_RELU><<<dim3(32, 32), 256, 0, stream>>>(h, W1T, b1 + l * 4096, a1,
                                                         2048, 4096, 1024);
    k_gemm_res<<<dim3(32, 16, 4), 256, 0, stream>>>(a1, W2T, b2 + l * 1024, x,
                                                    2048, 1024, 4096);
  }

  k_ln<<<2048, 256, 0, stream>>>(x, lnfs, lnfb, h);
  k_transpose<<<dim3(1000, 32), b32, 0, stream>>>(Wlm, arena, 1024, 32000);
  k_gemm_out<<<4000, 256, 0, stream>>>(h, arena, blm, out, 2048, 32000, 1024);
}

// Round 13
// 1069.318 us; speedup vs baseline: 1.0617x; 1.0617x over previous
//
#include <hip/hip_runtime.h>

typedef unsigned short u16;
typedef unsigned int u32;
typedef __bf16 bf16x8 __attribute__((ext_vector_type(8)));
typedef float f32x4 __attribute__((ext_vector_type(4)));
typedef u16 u16x8 __attribute__((ext_vector_type(8)));
typedef u16 u16x4 __attribute__((ext_vector_type(4)));

static __device__ __forceinline__ u16 f2bf(float f) {
  u32 u = __builtin_bit_cast(u32, f);
  u32 r = (u + 0x7FFFu + ((u >> 16) & 1u)) >> 16;  // RNE; inputs finite
  return (u16)r;
}

static __device__ __forceinline__ void atomAddF32(float* p, float v) {
  asm volatile("global_atomic_add_f32 %0, %1, off" :: "v"(p), "v"(v) : "memory");
}

#define GLOAD_LDS16(gp, lp)                                                   \
  __builtin_amdgcn_global_load_lds(                                           \
      (const __attribute__((address_space(1))) void*)(gp),                    \
      (__attribute__((address_space(3))) void*)(lp), 16, 0, 0)

#define MFB(a, b, cc) __builtin_amdgcn_mfma_f32_16x16x32_bf16(a, b, cc, 0, 0, 0)

// ---------------- fused embedding + layer-0 LN1 ----------------
__global__ void k_embed_ln(const int* __restrict__ idx, const float* __restrict__ tok,
                           const float* __restrict__ pos, const float* __restrict__ sc,
                           const float* __restrict__ bi, float* __restrict__ x,
                           u16* __restrict__ out) {
  int row = blockIdx.x;            // b*1024 + t
  int tt = row & 1023;
  int id = idx[row];
  int t = threadIdx.x;
  float4 a = *(const float4*)(tok + (size_t)id * 1024 + t * 4);
  float4 p = *(const float4*)(pos + (size_t)tt * 1024 + t * 4);
  float4 v{a.x + p.x, a.y + p.y, a.z + p.z, a.w + p.w};
  *(float4*)(x + (size_t)row * 1024 + t * 4) = v;
  float s = v.x + v.y + v.z + v.w;
  float ss = v.x * v.x + v.y * v.y + v.z * v.z + v.w * v.w;
  for (int d = 1; d < 64; d <<= 1) { s += __shfl_xor(s, d); ss += __shfl_xor(ss, d); }
  __shared__ float red[8];
  int wave = t >> 6, lane = t & 63;
  if (lane == 0) { red[wave] = s; red[wave + 4] = ss; }
  __syncthreads();
  s = red[0] + red[1] + red[2] + red[3];
  ss = red[4] + red[5] + red[6] + red[7];
  float mu = s * (1.0f / 1024.0f);
  float var = ss * (1.0f / 1024.0f) - mu * mu;
  float inv = rsqrtf(var + 1e-5f);
  float4 g = *(const float4*)(sc + t * 4);
  float4 b = *(const float4*)(bi + t * 4);
  u16x4 o;
  o[0] = f2bf((v.x - mu) * inv * g.x + b.x);
  o[1] = f2bf((v.y - mu) * inv * g.y + b.y);
  o[2] = f2bf((v.z - mu) * inv * g.z + b.z);
  o[3] = f2bf((v.w - mu) * inv * g.w + b.w);
  *(u16x4*)(out + (size_t)row * 1024 + t * 4) = o;
}

// ---------------- layernorm (f32 in) -> bf16 out ----------------
__global__ void k_ln(const float* __restrict__ x, const float* __restrict__ sc,
                     const float* __restrict__ bi, u16* __restrict__ out) {
  int row = blockIdx.x;
  int t = threadIdx.x;
  const float* xr = x + (size_t)row * 1024;
  float4 v = *(const float4*)(xr + t * 4);
  float s = v.x + v.y + v.z + v.w;
  float ss = v.x * v.x + v.y * v.y + v.z * v.z + v.w * v.w;
  for (int d = 1; d < 64; d <<= 1) { s += __shfl_xor(s, d); ss += __shfl_xor(ss, d); }
  __shared__ float red[8];
  int wave = t >> 6, lane = t & 63;
  if (lane == 0) { red[wave] = s; red[wave + 4] = ss; }
  __syncthreads();
  s = red[0] + red[1] + red[2] + red[3];
  ss = red[4] + red[5] + red[6] + red[7];
  float mu = s * (1.0f / 1024.0f);
  float var = ss * (1.0f / 1024.0f) - mu * mu;
  float inv = rsqrtf(var + 1e-5f);
  float4 g = *(const float4*)(sc + t * 4);
  float4 b = *(const float4*)(bi + t * 4);
  u16x4 o;
  o[0] = f2bf((v.x - mu) * inv * g.x + b.x);
  o[1] = f2bf((v.y - mu) * inv * g.y + b.y);
  o[2] = f2bf((v.z - mu) * inv * g.z + b.z);
  o[3] = f2bf((v.w - mu) * inv * g.w + b.w);
  *(u16x4*)(out + (size_t)row * 1024 + t * 4) = o;
}

// ---------------- transpose+convert: f32 src[R][C] -> bf16 dst[C][R] ----------------
__launch_bounds__(1024)
__global__ void k_transpose(const float* __restrict__ src, u16* __restrict__ dst,
                            int R, int C) {
  __shared__ float tile[32][33];
  int tx = threadIdx.x, ty = threadIdx.y;
  int c = blockIdx.x * 32 + tx;
  int r = blockIdx.y * 32 + ty;
  tile[ty][tx] = src[(size_t)r * C + c];
  __syncthreads();
  int dr = blockIdx.x * 32 + ty;
  int dc = blockIdx.y * 32 + tx;
  dst[(size_t)dr * R + dc] = f2bf(tile[tx][ty]);
}

// ---------------- fused per-layer weight transpose (6 matrices, 1 launch) ----------
__launch_bounds__(1024)
__global__ void k_transpose_layer(const float* __restrict__ Wq, const float* __restrict__ Wk,
                                  const float* __restrict__ Wv, const float* __restrict__ Wo,
                                  const float* __restrict__ W1, const float* __restrict__ W2,
                                  u16* __restrict__ qkvT, u16* __restrict__ WoT,
                                  u16* __restrict__ W1T, u16* __restrict__ W2T) {
  int bid = blockIdx.x;
  const float* src; u16* dst; int R, C, bx, by;
  if (bid < 4096) {
    int which = bid >> 10, tile_i = bid & 1023;
    bx = tile_i & 31; by = tile_i >> 5; R = 1024; C = 1024;
    src = which == 0 ? Wq : which == 1 ? Wk : which == 2 ? Wv : Wo;
    dst = which == 3 ? WoT : qkvT + (size_t)which * 1048576;
  } else if (bid < 8192) {
    int tile_i = bid - 4096; bx = tile_i & 127; by = tile_i >> 7; R = 1024; C = 4096;
    src = W1; dst = W1T;
  } else {
    int tile_i = bid - 8192; bx = tile_i & 31; by = tile_i >> 5; R = 4096; C = 1024;
    src = W2; dst = W2T;
  }
  __shared__ float tile[32][33];
  int tx = threadIdx.x, ty = threadIdx.y;
  int c = bx * 32 + tx, r = by * 32 + ty;
  tile[ty][tx] = src[(size_t)r * C + c];
  __syncthreads();
  int dr = bx * 32 + ty, dc = by * 32 + tx;
  dst[(size_t)dr * R + dc] = f2bf(tile[tx][ty]);
}

// ---------------- GEMMs: C[M][N] = A[M][K](bf16) x Bt[N][K](bf16)^T ----------------
enum { EPI_QKV = 0, EPI_RELU = 2 };

// 64x128 tile, 2-phase pipelined (QKV / RELU). LDS-staged coalesced epilogues.
template <int EPI>
__launch_bounds__(256, 4)
__global__ void k_gemm64(const u16* __restrict__ A, const u16* __restrict__ Bt,
                         const float* __restrict__ bias, u16* __restrict__ bout,
                         int M, int N, int K) {
  __shared__ alignas(16) u16 smem[12288];   // Al[2][64][32] | Bl[2][128][32]
#define AL(s, r, k) smem[(s)*2048 + (r)*32 + (k)]
#define BL(s, r, k) smem[4096 + (s)*4096 + (r)*32 + (k)]
  const int t = threadIdx.x;
  const int wave = t >> 6, lane = t & 63;
  const int wm = wave >> 1, wn = wave & 1;       // 2x2 waves: 32x64 out each
  const int g = lane >> 4, c = lane & 15;
  const int m0 = blockIdx.x * 64, n0 = blockIdx.y * 128;

  const int rwA = t >> 2, sgA = (t & 3) * 8;
  const u16* gA = A + (size_t)(m0 + rwA) * K + sgA;
  const u16* gB = Bt + (size_t)(n0 + rwA) * K + sgA;

  f32x4 acc[2][4] = {};
  const int nK = K >> 5;
  int cur = 0;

  GLOAD_LDS16(gA, &AL(0, rwA, 0));
#pragma unroll
  for (int p = 0; p < 2; ++p)
    GLOAD_LDS16(gB + (size_t)p * 64 * K, &BL(0, p * 64 + rwA, 0));
  __syncthreads();

  for (int kt = 0; kt < nK; ++kt) {
    if (kt + 1 < nK) {
      const int k0 = (kt + 1) << 5;
      GLOAD_LDS16(gA + k0, &AL(cur ^ 1, rwA, 0));
#pragma unroll
      for (int p = 0; p < 2; ++p)
        GLOAD_LDS16(gB + k0 + (size_t)p * 64 * K, &BL(cur ^ 1, p * 64 + rwA, 0));
    }
    bf16x8 af[2], bfr[4];
#pragma unroll
    for (int i = 0; i < 2; ++i)
      af[i] = *(const bf16x8*)&AL(cur, wm * 32 + i * 16 + c, g * 8);
#pragma unroll
    for (int j = 0; j < 4; ++j)
      bfr[j] = *(const bf16x8*)&BL(cur, wn * 64 + j * 16 + c, g * 8);
#pragma unroll
    for (int i = 0; i < 2; ++i)
#pragma unroll
      for (int j = 0; j < 4; ++j)
        acc[i][j] = MFB(af[i], bfr[j], acc[i][j]);
    __syncthreads();
    cur ^= 1;
  }

  if (EPI == EPI_QKV) {
    const int which = n0 >> 10;                  // 0=Q 1=K 2=V (uniform per block)
    const int b = m0 >> 10, t0 = m0 & 1023;
    const int hh0 = (n0 >> 6) & 15;
    if (which < 2) {
      const float qsc = (which == 0) ? 0.125f : 1.0f;   // pre-scale Q by 1/sqrt(HD)
      u16 (*Ct)[136] = (u16(*)[136])smem;
#pragma unroll
      for (int i = 0; i < 2; ++i)
#pragma unroll
        for (int j = 0; j < 4; ++j)
#pragma unroll
          for (int r = 0; r < 4; ++r)
            Ct[wm * 32 + i * 16 + g * 4 + r][wn * 64 + j * 16 + c] = f2bf(acc[i][j][r] * qsc);
      __syncthreads();
      u16* obase = bout + (size_t)which * 2097152;
#pragma unroll
      for (int itr = 0; itr < 4; ++itr) {
        int idx2 = itr * 256 + t;
        int s = idx2 >> 9;
        int tt = (idx2 >> 3) & 63;
        int seg = idx2 & 7;
        u16x8 vv = *(const u16x8*)&Ct[tt][s * 64 + seg * 8];
        *(u16x8*)(obase + ((size_t)(b * 16 + hh0 + s) * 1024 + (t0 + tt)) * 64 + seg * 8) = vv;
      }
    } else {
      // V transposed: stage [128 feat][72 tok], store [bh][d][t]
      u16 (*Cv)[72] = (u16(*)[72])smem;
#pragma unroll
      for (int i = 0; i < 2; ++i)
#pragma unroll
        for (int j = 0; j < 4; ++j) {
          u16x4 pk;
#pragma unroll
          for (int r = 0; r < 4; ++r) pk[r] = f2bf(acc[i][j][r]);
          *(u16x4*)&Cv[wn * 64 + j * 16 + c][wm * 32 + i * 16 + g * 4] = pk;
        }
      __syncthreads();
      u16* obase = bout + (size_t)2 * 2097152;
#pragma unroll
      for (int itr = 0; itr < 4; ++itr) {
        int idx2 = itr * 256 + t;
        int row = idx2 >> 3;
        int seg = idx2 & 7;
        int s = row >> 6, f = row & 63;
        u16x8 vv = *(const u16x8*)&Cv[row][seg * 8];
        *(u16x8*)(obase + ((size_t)(b * 16 + hh0 + s) * 64 + f) * 1024 + t0 + seg * 8) = vv;
      }
    }
  } else {  // EPI_RELU
    u16 (*Ct)[136] = (u16(*)[136])smem;
#pragma unroll
    for (int i = 0; i < 2; ++i)
#pragma unroll
      for (int j = 0; j < 4; ++j)
#pragma unroll
        for (int r = 0; r < 4; ++r) {
          float u = acc[i][j][r] + bias[n0 + wn * 64 + j * 16 + c];
          Ct[wm * 32 + i * 16 + g * 4 + r][wn * 64 + j * 16 + c] = f2bf(u > 0.f ? u : 0.f);
        }
    __syncthreads();
#pragma unroll
    for (int itr = 0; itr < 4; ++itr) {
      int idx2 = itr * 256 + t;
      int tt = idx2 >> 4, seg = idx2 & 15;
      *(u16x8*)(bout + (size_t)(m0 + tt) * N + n0 + seg * 8) =
          *(const u16x8*)&Ct[tt][seg * 8];
    }
  }
#undef AL
#undef BL
}

// 64x64 tile, 2-phase, SPLIT-K over gridDim.z; residual += via HW f32 atomics
__launch_bounds__(256, 8)
__global__ void k_gemm_res(const u16* __restrict__ A, const u16* __restrict__ Bt,
                           const float* __restrict__ bias, float* __restrict__ fout,
                           int M, int N, int K) {
  __shared__ alignas(16) u16 smem[8192];   // Al[2][64][32] | Bl[2][64][32]
  const int t = threadIdx.x;
  const int wave = t >> 6, lane = t & 63;
  const int wm = wave >> 1, wn = wave & 1;   // 2x2 waves: 32x32 out each
  const int g = lane >> 4, c = lane & 15;
  const int m0 = blockIdx.x * 64, n0 = blockIdx.y * 64;
  const int kz = blockIdx.z;
  const int Kh = K >> 1;                     // per-split K (z=2)
  const int kbase = kz * Kh;

  const int rw = t >> 2, sg = (t & 3) * 8;
  const u16* gA = A + (size_t)(m0 + rw) * K + kbase + sg;
  const u16* gB = Bt + (size_t)(n0 + rw) * K + kbase + sg;

  f32x4 acc[2][2] = {};
  const int nK = Kh >> 5;
  int cur = 0;

  GLOAD_LDS16(gA, &smem[rw * 32]);
  GLOAD_LDS16(gB, &smem[4096 + rw * 32]);
  __syncthreads();

  for (int kt = 0; kt < nK; ++kt) {
    if (kt + 1 < nK) {
      const int k0 = (kt + 1) << 5;
      GLOAD_LDS16(gA + k0, &smem[(cur ^ 1) * 2048 + rw * 32]);
      GLOAD_LDS16(gB + k0, &smem[4096 + (cur ^ 1) * 2048 + rw * 32]);
    }
    bf16x8 af[2], bfr[2];
#pragma unroll
    for (int i = 0; i < 2; ++i)
      af[i] = *(const bf16x8*)&smem[cur * 2048 + (wm * 32 + i * 16 + c) * 32 + g * 8];
#pragma unroll
    for (int j = 0; j < 2; ++j)
      bfr[j] = *(const bf16x8*)&smem[4096 + cur * 2048 + (wn * 32 + j * 16 + c) * 32 + g * 8];
#pragma unroll
    for (int i = 0; i < 2; ++i)
#pragma unroll
      for (int j = 0; j < 2; ++j)
        acc[i][j] = MFB(af[i], bfr[j], acc[i][j]);
    __syncthreads();
    cur ^= 1;
  }

#pragma unroll
  for (int i = 0; i < 2; ++i)
#pragma unroll
    for (int j = 0; j < 2; ++j)
#pragma unroll
      for (int r = 0; r < 4; ++r) {
        int m = m0 + wm * 32 + i * 16 + g * 4 + r;
        int n = n0 + wn * 32 + j * 16 + c;
        float v = acc[i][j][r] + (kz == 0 ? bias[n] : 0.f);
        atomAddF32(&fout[(size_t)m * N + n], v);
      }
}

// ---------------- GEMM 128x128 2-phase (LM head, f32+bias out), XCD swizzle ------
__launch_bounds__(256, 4)
__global__ void k_gemm_out(const u16* __restrict__ A, const u16* __restrict__ Bt,
                           const float* __restrict__ bias, float* __restrict__ fout,
                           int M, int N, int K) {
  __shared__ alignas(16) u16 sm[2][2][128][32];
  const int t = threadIdx.x;
  const int wave = t >> 6, lane = t & 63;
  const int wm = wave >> 1, wn = wave & 1;
  const int g = lane >> 4, c = lane & 15;
  // 4000 blocks = 8 XCDs x 500: bijective chunked swizzle; M fast within chunk
  const int wg = (blockIdx.x & 7) * 500 + (blockIdx.x >> 3);
  const int m0 = (wg & 15) * 128, n0 = (wg >> 4) * 128;

  const int srow = wave * 32 + (lane >> 2);
  const int sseg = (lane & 3) * 8;
  const u16* gA = A + (size_t)(m0 + srow) * K + sseg;
  const u16* gB = Bt + (size_t)(n0 + srow) * K + sseg;

  f32x4 acc[4][4] = {};
  const int nK = K >> 5;
  int cur = 0;

#pragma unroll
  for (int p = 0; p < 2; ++p) {
    GLOAD_LDS16(gA + (size_t)p * 16 * K, &sm[0][0][wave * 32 + p * 16][0]);
    GLOAD_LDS16(gB + (size_t)p * 16 * K, &sm[0][1][wave * 32 + p * 16][0]);
  }
  __syncthreads();

  for (int kt = 0; kt < nK; ++kt) {
    if (kt + 1 < nK) {
      const int k0 = (kt + 1) << 5;
#pragma unroll
      for (int p = 0; p < 2; ++p) {
        GLOAD_LDS16(gA + k0 + (size_t)p * 16 * K, &sm[cur ^ 1][0][wave * 32 + p * 16][0]);
        GLOAD_LDS16(gB + k0 + (size_t)p * 16 * K, &sm[cur ^ 1][1][wave * 32 + p * 16][0]);
      }
    }
    bf16x8 af[4], bfr[4];
#pragma unroll
    for (int i = 0; i < 4; ++i) {
      af[i]  = *(const bf16x8*)&sm[cur][0][wm * 64 + i * 16 + c][g * 8];
      bfr[i] = *(const bf16x8*)&sm[cur][1][wn * 64 + i * 16 + c][g * 8];
    }
#pragma unroll
    for (int i = 0; i < 4; ++i)
#pragma unroll
      for (int j = 0; j < 4; ++j)
        acc[i][j] = MFB(af[i], bfr[j], acc[i][j]);
    __syncthreads();
    cur ^= 1;
  }

  float (*st)[132] = (float(*)[132])sm;
#pragma unroll
  for (int i = 0; i < 4; ++i) {
#pragma unroll
    for (int j = 0; j < 4; ++j)
#pragma unroll
      for (int r = 0; r < 4; ++r)
        st[wm * 16 + g * 4 + r][wn * 64 + j * 16 + c] = acc[i][j][r];
    __syncthreads();
    {
      int row = t >> 3;
      int cs = (t & 7) * 16;
      int m = m0 + (row >> 4) * 64 + i * 16 + (row & 15);
      float* dst = fout + (size_t)m * N + n0 + cs;
#pragma unroll
      for (int q = 0; q < 4; ++q) {
        float4 v = *(const float4*)&st[row][cs + q * 4];
        float4 bb = *(const float4*)&bias[n0 + cs + q * 4];
        float4 o{v.x + bb.x, v.y + bb.y, v.z + bb.z, v.w + bb.w};
        *(float4*)(dst + q * 4) = o;
      }
    }
    __syncthreads();
  }
}

// ---------------- flash attention: K-split across 2 waves + merge ----------------
// Q pre-scaled by 1/8; mask only diagonal tile; per-lane deferred L-reduction.
#define AITER(ITV, MASKED)                                                    \
  {                                                                           \
    const int k0 = (ITV) << 5;                                                \
    bf16x8 kb0 = *(const bf16x8*)(Kh + (k0 + c) * 64 + g * 8);                \
    bf16x8 kb1 = *(const bf16x8*)(Kh + (k0 + c) * 64 + 32 + g * 8);           \
    bf16x8 kb2 = *(const bf16x8*)(Kh + (k0 + 16 + c) * 64 + g * 8);           \
    bf16x8 kb3 = *(const bf16x8*)(Kh + (k0 + 16 + c) * 64 + 32 + g * 8);      \
    bf16x8 bv0 = *(const bf16x8*)(VTh + (size_t)(c) * 1024 + k0 + g * 8);     \
    bf16x8 bv1 = *(const bf16x8*)(VTh + (size_t)(16 + c) * 1024 + k0 + g * 8);\
    bf16x8 bv2 = *(const bf16x8*)(VTh + (size_t)(32 + c) * 1024 + k0 + g * 8);\
    bf16x8 bv3 = *(const bf16x8*)(VTh + (size_t)(48 + c) * 1024 + k0 + g * 8);\
    f32x4 S[2][2];                                                            \
    __builtin_amdgcn_s_setprio(1);                                            \
    _Pragma("unroll") for (int qt = 0; qt < 2; ++qt) {                        \
      f32x4 z = {};                                                           \
      S[qt][0] = MFB(aq[qt][1], kb1, MFB(aq[qt][0], kb0, z));                 \
      S[qt][1] = MFB(aq[qt][1], kb3, MFB(aq[qt][0], kb2, z));                 \
    }                                                                         \
    __builtin_amdgcn_s_setprio(0);                                            \
    float sv[2][2][4], mt[2][4];                                              \
    float need = 0.0f;                                                        \
    _Pragma("unroll") for (int qt = 0; qt < 2; ++qt)                          \
      _Pragma("unroll") for (int r = 0; r < 4; ++r) {                         \
        float s0 = S[qt][0][r], s1 = S[qt][1][r];                             \
        if (MASKED) {                                                         \
          int q = q0 + qt * 16 + (g << 2) + r;                                \
          s0 = (k0 + c <= q) ? s0 : -1e30f;                                   \
          s1 = (k0 + 16 + c <= q) ? s1 : -1e30f;                              \
        }                                                                     \
        sv[qt][0][r] = s0; sv[qt][1][r] = s1;                                 \
        float m = fmaxf(s0, s1);                                              \
        m = fmaxf(m, __shfl_xor(m, 1));                                       \
        m = fmaxf(m, __shfl_xor(m, 2));                                       \
        m = fmaxf(m, __shfl_xor(m, 4));                                       \
        m = fmaxf(m, __shfl_xor(m, 8));                                       \
        mt[qt][r] = m;                                                        \
        need = fmaxf(need, m - Mr[qt][r]);                                    \
      }                                                                       \
    unsigned long long vote = __ballot(need <= 8.0f);                         \
    const bool nore = wv ? ((vote & 0xFFFFFFFF00000000ull) == 0xFFFFFFFF00000000ull) \
                         : ((vote & 0xFFFFFFFFull) == 0xFFFFFFFFull);         \
    _Pragma("unroll") for (int qt = 0; qt < 2; ++qt)                          \
      _Pragma("unroll") for (int r = 0; r < 4; ++r) {                         \
        float mn = nore ? Mr[qt][r] : fmaxf(Mr[qt][r], mt[qt][r]);            \
        float p0 = __expf(sv[qt][0][r] - mn);                                 \
        float p1 = __expf(sv[qt][1][r] - mn);                                 \
        if (nore) {                                                           \
          Lr[qt][r] += p0 + p1;       /* per-lane partial; reduced at end */  \
        } else {                                                              \
          float alpha = __expf(Mr[qt][r] - mn);                               \
          Lr[qt][r] = Lr[qt][r] * alpha + p0 + p1;                            \
          Mr[qt][r] = mn;                                                     \
          _Pragma("unroll") for (int nb = 0; nb < 4; ++nb) Oacc[qt][nb][r] *= alpha; \
        }                                                                     \
        Pl[wv][qt * 16 + (g << 2) + r][c] = f2bf(p0);                         \
        Pl[wv][qt * 16 + (g << 2) + r][16 + c] = f2bf(p1);                    \
      }                                                                       \
    __builtin_amdgcn_s_setprio(1);                                            \
    _Pragma("unroll") for (int qt = 0; qt < 2; ++qt) {                        \
      bf16x8 ap = *(const bf16x8*)&Pl[wv][qt * 16 + c][g * 8];                \
      Oacc[qt][0] = MFB(ap, bv0, Oacc[qt][0]);                                \
      Oacc[qt][1] = MFB(ap, bv1, Oacc[qt][1]);                                \
      Oacc[qt][2] = MFB(ap, bv2, Oacc[qt][2]);                                \
      Oacc[qt][3] = MFB(ap, bv3, Oacc[qt][3]);                                \
    }                                                                         \
    __builtin_amdgcn_s_setprio(0);                                            \
  }

__launch_bounds__(128)
__global__ void k_attn(const u16* __restrict__ Q, const u16* __restrict__ Kb,
                       const u16* __restrict__ VT, u16* __restrict__ O) {
  const int qb = 31 - blockIdx.x;  // heavy blocks dispatch first
  const int bh = blockIdx.y;       // 0..31
  const int tid = threadIdx.x;
  const int wv = tid >> 6;         // wave 0/1: lower/upper K half
  const int lane = tid & 63;
  const int g = lane >> 4, c = lane & 15;
  const int q0 = qb << 5;
  const u16* Qh = Q + (size_t)bh * 65536;
  const u16* Kh = Kb + (size_t)bh * 65536;
  const u16* VTh = VT + (size_t)bh * 65536;

  __shared__ u16 Pl[2][32][40];
  __shared__ float mrg[64][48];

  bf16x8 aq[2][2];
#pragma unroll
  for (int qt = 0; qt < 2; ++qt) {
    aq[qt][0] = *(const bf16x8*)(Qh + (q0 + qt * 16 + c) * 64 + g * 8);
    aq[qt][1] = *(const bf16x8*)(Qh + (q0 + qt * 16 + c) * 64 + 32 + g * 8);
  }

  f32x4 Oacc[2][4] = {};
  float Mr[2][4], Lr[2][4] = {};
#pragma unroll
  for (int qt = 0; qt < 2; ++qt)
#pragma unroll
    for (int r = 0; r < 4; ++r) Mr[qt][r] = -1e30f;

  const int nIt = qb + 1;
  const int half = (nIt + 1) >> 1;

  if (wv == 0) {
    if (qb == 0) {
      AITER(0, 1);
    } else {
      for (int it = 0; it < half; ++it) AITER(it, 0);   // all < qb: unmasked
    }
  } else {
    for (int it = half; it < nIt - 1; ++it) AITER(it, 0);
    if (qb >= 1) AITER(nIt - 1, 1);                      // diagonal tile
  }

  // merge: wave1 publishes partial state; wave0 combines, reduces L, writes out
  if (wv == 1) {
#pragma unroll
    for (int qt = 0; qt < 2; ++qt) {
#pragma unroll
      for (int nb = 0; nb < 4; ++nb)
#pragma unroll
        for (int r = 0; r < 4; ++r)
          mrg[lane][qt * 16 + nb * 4 + r] = Oacc[qt][nb][r];
#pragma unroll
      for (int r = 0; r < 4; ++r) {
        mrg[lane][32 + qt * 4 + r] = Mr[qt][r];
        mrg[lane][40 + qt * 4 + r] = Lr[qt][r];
      }
    }
  }
  __syncthreads();
  if (wv == 0) {
    const int b = bh >> 4, hh = bh & 15;
#pragma unroll
    for (int qt = 0; qt < 2; ++qt)
#pragma unroll
      for (int r = 0; r < 4; ++r) {
        float m1 = mrg[lane][32 + qt * 4 + r];
        float l1 = mrg[lane][40 + qt * 4 + r];
        float mm = fmaxf(Mr[qt][r], m1);
        float a0 = __expf(Mr[qt][r] - mm);
        float a1 = __expf(m1 - mm);
        float l = a0 * Lr[qt][r] + a1 * l1;   // per-lane partial
        l += __shfl_xor(l, 1);
        l += __shfl_xor(l, 2);
        l += __shfl_xor(l, 4);
        l += __shfl_xor(l, 8);
        float invl = 1.0f / l;
        int tt = q0 + qt * 16 + (g << 2) + r;
#pragma unroll
        for (int nb = 0; nb < 4; ++nb) {
          float o1 = mrg[lane][qt * 16 + nb * 4 + r];
          float val = (a0 * Oacc[qt][nb][r] + a1 * o1) * invl;
          int d = nb * 16 + c;
          O[((size_t)(b * 1024 + tt)) * 1024 + hh * 64 + d] = f2bf(val);
        }
      }
  }
}

// ---------------- launch ----------------
extern "C" void kernel_launch(void* const* d_in, const int* in_sizes, int n_in,
                              void* d_out, int out_size, void* d_ws, size_t ws_size,
                              hipStream_t stream) {
  const int*   idx  = (const int*)d_in[0];
  const float* tok  = (const float*)d_in[1];
  const float* pos  = (const float*)d_in[2];
  const float* Wq   = (const float*)d_in[3];
  const float* Wk   = (const float*)d_in[4];
  const float* Wv   = (const float*)d_in[5];
  const float* Wo   = (const float*)d_in[6];
  const float* bo   = (const float*)d_in[7];
  const float* ln1s = (const float*)d_in[8];
  const float* ln1b = (const float*)d_in[9];
  const float* ln2s = (const float*)d_in[10];
  const float* ln2b = (const float*)d_in[11];
  const float* W1   = (const float*)d_in[12];
  const float* b1   = (const float*)d_in[13];
  const float* W2   = (const float*)d_in[14];
  const float* b2   = (const float*)d_in[15];
  const float* lnfs = (const float*)d_in[16];
  const float* lnfb = (const float*)d_in[17];
  const float* Wlm  = (const float*)d_in[18];
  const float* blm  = (const float*)d_in[19];
  float* out = (float*)d_out;

  char* w = (char*)d_ws;
  auto alloc = [&](size_t bytes) {
    char* p = w;
    w += (bytes + 255) & ~(size_t)255;
    return p;
  };
  float* x  = (float*)alloc(2048ull * 1024 * 4);
  u16* h    = (u16*)alloc(2048ull * 1024 * 2);
  u16* qkv  = (u16*)alloc(3ull * 2097152 * 2);   // Q,K: [bh][t][64]; V: [bh][d][t]
  u16* o    = (u16*)alloc(2048ull * 1024 * 2);
  u16* a1   = (u16*)alloc(2048ull * 4096 * 2);
  u16* arena = (u16*)alloc(32000ull * 1024 * 2);

  dim3 b32(32, 32, 1);

  k_embed_ln<<<2048, 256, 0, stream>>>(idx, tok, pos, ln1s, ln1b, x, h);

  for (int l = 0; l < 4; ++l) {
    u16* qkvT = arena;
    u16* WoT  = arena + 3ull * 1048576;
    u16* W1T  = arena + 4ull * 1048576;
    u16* W2T  = arena + 8ull * 1048576;
    k_transpose_layer<<<12288, b32, 0, stream>>>(
        Wq + (size_t)l * 1048576, Wk + (size_t)l * 1048576,
        Wv + (size_t)l * 1048576, Wo + (size_t)l * 1048576,
        W1 + (size_t)l * 4194304, W2 + (size_t)l * 4194304,
        qkvT, WoT, W1T, W2T);

    if (l > 0)
      k_ln<<<2048, 256, 0, stream>>>(x, ln1s + l * 1024, ln1b + l * 1024, h);
    k_gemm64<EPI_QKV><<<dim3(32, 24), 256, 0, stream>>>(h, qkvT, nullptr, qkv,
                                                        2048, 3072, 1024);
    k_attn<<<dim3(32, 32), 128, 0, stream>>>(qkv, qkv + 2097152, qkv + 2 * 2097152, o);
    k_gemm_res<<<dim3(32, 16, 2), 256, 0, stream>>>(o, WoT, bo + l * 1024, x,
                                                    2048, 1024, 1024);
    k_ln<<<2048, 256, 0, stream>>>(x, ln2s + l * 1024, ln2b + l * 1024, h);
    k_gemm64<EPI_RELU><<<dim3(32, 32), 256, 0, stream>>>(h, W1T, b1 + l * 4096, a1,
                                                         2048, 4096, 1024);
    k_gemm_res<<<dim3(32, 16, 2), 256, 0, stream>>>(a1, W2T, b2 + l * 1024, x,
                                                    2048, 1024, 4096);
  }

  k_ln<<<2048, 256, 0, stream>>>(x, lnfs, lnfb, h);
  k_transpose<<<dim3(1000, 32), b32, 0, stream>>>(Wlm, arena, 1024, 32000);
  k_gemm_out<<<4000, 256, 0, stream>>>(h, arena, blm, out, 2048, 32000, 1024);
}

// Round 14
// 1056.823 us; speedup vs baseline: 1.0742x; 1.0118x over previous
//
#include <hip/hip_runtime.h>

typedef unsigned short u16;
typedef unsigned int u32;
typedef __bf16 bf16x8 __attribute__((ext_vector_type(8)));
typedef float f32x4 __attribute__((ext_vector_type(4)));
typedef u16 u16x8 __attribute__((ext_vector_type(8)));
typedef u16 u16x4 __attribute__((ext_vector_type(4)));

static __device__ __forceinline__ u16 f2bf(float f) {
  u32 u = __builtin_bit_cast(u32, f);
  u32 r = (u + 0x7FFFu + ((u >> 16) & 1u)) >> 16;  // RNE; inputs finite
  return (u16)r;
}

static __device__ __forceinline__ void atomAddF32(float* p, float v) {
  asm volatile("global_atomic_add_f32 %0, %1, off" :: "v"(p), "v"(v) : "memory");
}

#define GLOAD_LDS16(gp, lp)                                                   \
  __builtin_amdgcn_global_load_lds(                                           \
      (const __attribute__((address_space(1))) void*)(gp),                    \
      (__attribute__((address_space(3))) void*)(lp), 16, 0, 0)

#define MFB(a, b, cc) __builtin_amdgcn_mfma_f32_16x16x32_bf16(a, b, cc, 0, 0, 0)

// ---- shared LN body for 1024-thread fused kernels: 4 rows/block ----
// tid in [0,1024): sub=row-in-block (tid>>8), t=col-thread (tid&255).
static __device__ __forceinline__ void ln4_body(
    int tid, int row, const float* __restrict__ xr,
    const float* __restrict__ sc, const float* __restrict__ bi,
    u16* __restrict__ out, float* red /* [16][2] */) {
  const int sub = tid >> 8, t = tid & 255;
  float4 v = *(const float4*)(xr + t * 4);
  float s = v.x + v.y + v.z + v.w;
  float ss = v.x * v.x + v.y * v.y + v.z * v.z + v.w * v.w;
  for (int d = 1; d < 64; d <<= 1) { s += __shfl_xor(s, d); ss += __shfl_xor(ss, d); }
  int wv = tid >> 6, lane = tid & 63;
  if (lane == 0) { red[wv * 2] = s; red[wv * 2 + 1] = ss; }
  __syncthreads();
  s = red[sub * 8] + red[sub * 8 + 2] + red[sub * 8 + 4] + red[sub * 8 + 6];
  ss = red[sub * 8 + 1] + red[sub * 8 + 3] + red[sub * 8 + 5] + red[sub * 8 + 7];
  float mu = s * (1.0f / 1024.0f);
  float var = ss * (1.0f / 1024.0f) - mu * mu;
  float inv = rsqrtf(var + 1e-5f);
  float4 g = *(const float4*)(sc + t * 4);
  float4 b = *(const float4*)(bi + t * 4);
  u16x4 o;
  o[0] = f2bf((v.x - mu) * inv * g.x + b.x);
  o[1] = f2bf((v.y - mu) * inv * g.y + b.y);
  o[2] = f2bf((v.z - mu) * inv * g.z + b.z);
  o[3] = f2bf((v.w - mu) * inv * g.w + b.w);
  *(u16x4*)(out + (size_t)row * 1024 + t * 4) = o;
}

// ---- shared per-layer weight-transpose block body (bid < 12288) ----
static __device__ __forceinline__ void transpose_layer_body(
    int bid, const float* Wq, const float* Wk, const float* Wv, const float* Wo,
    const float* W1, const float* W2, u16* qkvT, u16* WoT, u16* W1T, u16* W2T,
    float (*tile)[33]) {
  const float* src; u16* dst; int R, C, bx, by;
  if (bid < 4096) {
    int which = bid >> 10, tile_i = bid & 1023;
    bx = tile_i & 31; by = tile_i >> 5; R = 1024; C = 1024;
    src = which == 0 ? Wq : which == 1 ? Wk : which == 2 ? Wv : Wo;
    dst = which == 3 ? WoT : qkvT + (size_t)which * 1048576;
  } else if (bid < 8192) {
    int tile_i = bid - 4096; bx = tile_i & 127; by = tile_i >> 7; R = 1024; C = 4096;
    src = W1; dst = W1T;
  } else {
    int tile_i = bid - 8192; bx = tile_i & 31; by = tile_i >> 5; R = 4096; C = 1024;
    src = W2; dst = W2T;
  }
  int tx = threadIdx.x, ty = threadIdx.y;
  int c = bx * 32 + tx, r = by * 32 + ty;
  tile[ty][tx] = src[(size_t)r * C + c];
  __syncthreads();
  int dr = bx * 32 + ty, dc = by * 32 + tx;
  dst[(size_t)dr * R + dc] = f2bf(tile[tx][ty]);
}

// ---------------- fused: layer-0 weight transpose + embed + LN1 ----------------
__launch_bounds__(1024)
__global__ void k_trans_embed_ln(const float* __restrict__ Wq, const float* __restrict__ Wk,
                                 const float* __restrict__ Wv, const float* __restrict__ Wo,
                                 const float* __restrict__ W1, const float* __restrict__ W2,
                                 u16* __restrict__ qkvT, u16* __restrict__ WoT,
                                 u16* __restrict__ W1T, u16* __restrict__ W2T,
                                 const int* __restrict__ idx, const float* __restrict__ tok,
                                 const float* __restrict__ pos, const float* __restrict__ sc,
                                 const float* __restrict__ bi, float* __restrict__ x,
                                 u16* __restrict__ hout) {
  __shared__ float tile[32][33];
  __shared__ float red[32];
  int bid = blockIdx.x;
  if (bid < 12288) {
    transpose_layer_body(bid, Wq, Wk, Wv, Wo, W1, W2, qkvT, WoT, W1T, W2T, tile);
    return;
  }
  // embed + LN: 4 rows per block (512 blocks -> 2048 rows)
  int tid = threadIdx.y * 32 + threadIdx.x;
  int sub = tid >> 8, t = tid & 255;
  int row = (bid - 12288) * 4 + sub;
  int tt = row & 1023;
  int id = idx[row];
  float4 a = *(const float4*)(tok + (size_t)id * 1024 + t * 4);
  float4 p = *(const float4*)(pos + (size_t)tt * 1024 + t * 4);
  float4 v{a.x + p.x, a.y + p.y, a.z + p.z, a.w + p.w};
  float* xr = x + (size_t)row * 1024;
  *(float4*)(xr + t * 4) = v;
  // LN over the just-computed row (v already in regs; ln4_body reloads from xr —
  // keep it simple and correct: recompute from v here instead)
  float s = v.x + v.y + v.z + v.w;
  float ss = v.x * v.x + v.y * v.y + v.z * v.z + v.w * v.w;
  for (int d = 1; d < 64; d <<= 1) { s += __shfl_xor(s, d); ss += __shfl_xor(ss, d); }
  int wv = tid >> 6, lane = tid & 63;
  if (lane == 0) { red[wv * 2] = s; red[wv * 2 + 1] = ss; }
  __syncthreads();
  s = red[sub * 8] + red[sub * 8 + 2] + red[sub * 8 + 4] + red[sub * 8 + 6];
  ss = red[sub * 8 + 1] + red[sub * 8 + 3] + red[sub * 8 + 5] + red[sub * 8 + 7];
  float mu = s * (1.0f / 1024.0f);
  float var = ss * (1.0f / 1024.0f) - mu * mu;
  float inv = rsqrtf(var + 1e-5f);
  float4 g = *(const float4*)(sc + t * 4);
  float4 b = *(const float4*)(bi + t * 4);
  u16x4 o;
  o[0] = f2bf((v.x - mu) * inv * g.x + b.x);
  o[1] = f2bf((v.y - mu) * inv * g.y + b.y);
  o[2] = f2bf((v.z - mu) * inv * g.z + b.z);
  o[3] = f2bf((v.w - mu) * inv * g.w + b.w);
  *(u16x4*)(hout + (size_t)row * 1024 + t * 4) = o;
}

// ---------------- fused: layer-l weight transpose + LN1 (l>0) ----------------
__launch_bounds__(1024)
__global__ void k_trans_ln_layer(const float* __restrict__ Wq, const float* __restrict__ Wk,
                                 const float* __restrict__ Wv, const float* __restrict__ Wo,
                                 const float* __restrict__ W1, const float* __restrict__ W2,
                                 u16* __restrict__ qkvT, u16* __restrict__ WoT,
                                 u16* __restrict__ W1T, u16* __restrict__ W2T,
                                 const float* __restrict__ x, const float* __restrict__ sc,
                                 const float* __restrict__ bi, u16* __restrict__ hout) {
  __shared__ float tile[32][33];
  __shared__ float red[32];
  int bid = blockIdx.x;
  if (bid < 12288) {
    transpose_layer_body(bid, Wq, Wk, Wv, Wo, W1, W2, qkvT, WoT, W1T, W2T, tile);
    return;
  }
  int tid = threadIdx.y * 32 + threadIdx.x;
  int row = (bid - 12288) * 4 + (tid >> 8);
  ln4_body(tid, row, x + (size_t)row * 1024, sc, bi, hout, red);
}

// ---------------- fused: final LN + Wlm transpose ----------------
__launch_bounds__(1024)
__global__ void k_lnf_transwlm(const float* __restrict__ Wlm, u16* __restrict__ dst,
                               const float* __restrict__ x, const float* __restrict__ sc,
                               const float* __restrict__ bi, u16* __restrict__ hout) {
  __shared__ float tile[32][33];
  __shared__ float red[32];
  int bid = blockIdx.x;
  if (bid < 32000) {
    // transpose f32 Wlm[1024][32000] -> bf16 dst[32000][1024]
    int bx = bid % 1000, by = bid / 1000;   // C-tile, R-tile
    int tx = threadIdx.x, ty = threadIdx.y;
    int c = bx * 32 + tx, r = by * 32 + ty;
    tile[ty][tx] = Wlm[(size_t)r * 32000 + c];
    __syncthreads();
    int dr = bx * 32 + ty, dc = by * 32 + tx;
    dst[(size_t)dr * 1024 + dc] = f2bf(tile[tx][ty]);
    return;
  }
  int tid = threadIdx.y * 32 + threadIdx.x;
  int row = (bid - 32000) * 4 + (tid >> 8);
  ln4_body(tid, row, x + (size_t)row * 1024, sc, bi, hout, red);
}

// ---------------- layernorm (f32 in) -> bf16 out (LN2, standalone) ----------------
__global__ void k_ln(const float* __restrict__ x, const float* __restrict__ sc,
                     const float* __restrict__ bi, u16* __restrict__ out) {
  int row = blockIdx.x;
  int t = threadIdx.x;
  const float* xr = x + (size_t)row * 1024;
  float4 v = *(const float4*)(xr + t * 4);
  float s = v.x + v.y + v.z + v.w;
  float ss = v.x * v.x + v.y * v.y + v.z * v.z + v.w * v.w;
  for (int d = 1; d < 64; d <<= 1) { s += __shfl_xor(s, d); ss += __shfl_xor(ss, d); }
  __shared__ float red[8];
  int wave = t >> 6, lane = t & 63;
  if (lane == 0) { red[wave] = s; red[wave + 4] = ss; }
  __syncthreads();
  s = red[0] + red[1] + red[2] + red[3];
  ss = red[4] + red[5] + red[6] + red[7];
  float mu = s * (1.0f / 1024.0f);
  float var = ss * (1.0f / 1024.0f) - mu * mu;
  float inv = rsqrtf(var + 1e-5f);
  float4 g = *(const float4*)(sc + t * 4);
  float4 b = *(const float4*)(bi + t * 4);
  u16x4 o;
  o[0] = f2bf((v.x - mu) * inv * g.x + b.x);
  o[1] = f2bf((v.y - mu) * inv * g.y + b.y);
  o[2] = f2bf((v.z - mu) * inv * g.z + b.z);
  o[3] = f2bf((v.w - mu) * inv * g.w + b.w);
  *(u16x4*)(out + (size_t)row * 1024 + t * 4) = o;
}

// ---------------- GEMMs: C[M][N] = A[M][K](bf16) x Bt[N][K](bf16)^T ----------------
enum { EPI_QKV = 0, EPI_RELU = 2 };

// 64x128 tile, 2-phase pipelined (QKV / RELU). LDS-staged coalesced epilogues.
template <int EPI>
__launch_bounds__(256, 4)
__global__ void k_gemm64(const u16* __restrict__ A, const u16* __restrict__ Bt,
                         const float* __restrict__ bias, u16* __restrict__ bout,
                         int M, int N, int K) {
  __shared__ alignas(16) u16 smem[12288];   // Al[2][64][32] | Bl[2][128][32]
#define AL(s, r, k) smem[(s)*2048 + (r)*32 + (k)]
#define BL(s, r, k) smem[4096 + (s)*4096 + (r)*32 + (k)]
  const int t = threadIdx.x;
  const int wave = t >> 6, lane = t & 63;
  const int wm = wave >> 1, wn = wave & 1;       // 2x2 waves: 32x64 out each
  const int g = lane >> 4, c = lane & 15;
  const int m0 = blockIdx.x * 64, n0 = blockIdx.y * 128;

  const int rwA = t >> 2, sgA = (t & 3) * 8;
  const u16* gA = A + (size_t)(m0 + rwA) * K + sgA;
  const u16* gB = Bt + (size_t)(n0 + rwA) * K + sgA;

  f32x4 acc[2][4] = {};
  const int nK = K >> 5;
  int cur = 0;

  GLOAD_LDS16(gA, &AL(0, rwA, 0));
#pragma unroll
  for (int p = 0; p < 2; ++p)
    GLOAD_LDS16(gB + (size_t)p * 64 * K, &BL(0, p * 64 + rwA, 0));
  __syncthreads();

  for (int kt = 0; kt < nK; ++kt) {
    if (kt + 1 < nK) {
      const int k0 = (kt + 1) << 5;
      GLOAD_LDS16(gA + k0, &AL(cur ^ 1, rwA, 0));
#pragma unroll
      for (int p = 0; p < 2; ++p)
        GLOAD_LDS16(gB + k0 + (size_t)p * 64 * K, &BL(cur ^ 1, p * 64 + rwA, 0));
    }
    bf16x8 af[2], bfr[4];
#pragma unroll
    for (int i = 0; i < 2; ++i)
      af[i] = *(const bf16x8*)&AL(cur, wm * 32 + i * 16 + c, g * 8);
#pragma unroll
    for (int j = 0; j < 4; ++j)
      bfr[j] = *(const bf16x8*)&BL(cur, wn * 64 + j * 16 + c, g * 8);
#pragma unroll
    for (int i = 0; i < 2; ++i)
#pragma unroll
      for (int j = 0; j < 4; ++j)
        acc[i][j] = MFB(af[i], bfr[j], acc[i][j]);
    __syncthreads();
    cur ^= 1;
  }

  if (EPI == EPI_QKV) {
    const int which = n0 >> 10;                  // 0=Q 1=K 2=V (uniform per block)
    const int b = m0 >> 10, t0 = m0 & 1023;
    const int hh0 = (n0 >> 6) & 15;
    if (which < 2) {
      const float qsc = (which == 0) ? 0.125f : 1.0f;   // pre-scale Q by 1/sqrt(HD)
      u16 (*Ct)[136] = (u16(*)[136])smem;
#pragma unroll
      for (int i = 0; i < 2; ++i)
#pragma unroll
        for (int j = 0; j < 4; ++j)
#pragma unroll
          for (int r = 0; r < 4; ++r)
            Ct[wm * 32 + i * 16 + g * 4 + r][wn * 64 + j * 16 + c] = f2bf(acc[i][j][r] * qsc);
      __syncthreads();
      u16* obase = bout + (size_t)which * 2097152;
#pragma unroll
      for (int itr = 0; itr < 4; ++itr) {
        int idx2 = itr * 256 + t;
        int s = idx2 >> 9;
        int tt = (idx2 >> 3) & 63;
        int seg = idx2 & 7;
        u16x8 vv = *(const u16x8*)&Ct[tt][s * 64 + seg * 8];
        *(u16x8*)(obase + ((size_t)(b * 16 + hh0 + s) * 1024 + (t0 + tt)) * 64 + seg * 8) = vv;
      }
    } else {
      // V transposed: stage [128 feat][72 tok], store [bh][d][t]
      u16 (*Cv)[72] = (u16(*)[72])smem;
#pragma unroll
      for (int i = 0; i < 2; ++i)
#pragma unroll
        for (int j = 0; j < 4; ++j) {
          u16x4 pk;
#pragma unroll
          for (int r = 0; r < 4; ++r) pk[r] = f2bf(acc[i][j][r]);
          *(u16x4*)&Cv[wn * 64 + j * 16 + c][wm * 32 + i * 16 + g * 4] = pk;
        }
      __syncthreads();
      u16* obase = bout + (size_t)2 * 2097152;
#pragma unroll
      for (int itr = 0; itr < 4; ++itr) {
        int idx2 = itr * 256 + t;
        int row = idx2 >> 3;
        int seg = idx2 & 7;
        int s = row >> 6, f = row & 63;
        u16x8 vv = *(const u16x8*)&Cv[row][seg * 8];
        *(u16x8*)(obase + ((size_t)(b * 16 + hh0 + s) * 64 + f) * 1024 + t0 + seg * 8) = vv;
      }
    }
  } else {  // EPI_RELU
    u16 (*Ct)[136] = (u16(*)[136])smem;
#pragma unroll
    for (int i = 0; i < 2; ++i)
#pragma unroll
      for (int j = 0; j < 4; ++j)
#pragma unroll
        for (int r = 0; r < 4; ++r) {
          float u = acc[i][j][r] + bias[n0 + wn * 64 + j * 16 + c];
          Ct[wm * 32 + i * 16 + g * 4 + r][wn * 64 + j * 16 + c] = f2bf(u > 0.f ? u : 0.f);
        }
    __syncthreads();
#pragma unroll
    for (int itr = 0; itr < 4; ++itr) {
      int idx2 = itr * 256 + t;
      int tt = idx2 >> 4, seg = idx2 & 15;
      *(u16x8*)(bout + (size_t)(m0 + tt) * N + n0 + seg * 8) =
          *(const u16x8*)&Ct[tt][seg * 8];
    }
  }
#undef AL
#undef BL
}

// 64x64 tile, 2-phase, SPLIT-K over gridDim.z; residual += via HW f32 atomics
__launch_bounds__(256, 8)
__global__ void k_gemm_res(const u16* __restrict__ A, const u16* __restrict__ Bt,
                           const float* __restrict__ bias, float* __restrict__ fout,
                           int M, int N, int K) {
  __shared__ alignas(16) u16 smem[8192];   // Al[2][64][32] | Bl[2][64][32]
  const int t = threadIdx.x;
  const int wave = t >> 6, lane = t & 63;
  const int wm = wave >> 1, wn = wave & 1;   // 2x2 waves: 32x32 out each
  const int g = lane >> 4, c = lane & 15;
  const int m0 = blockIdx.x * 64, n0 = blockIdx.y * 64;
  const int kz = blockIdx.z;
  const int Kh = K >> 1;                     // per-split K (z=2)
  const int kbase = kz * Kh;

  const int rw = t >> 2, sg = (t & 3) * 8;
  const u16* gA = A + (size_t)(m0 + rw) * K + kbase + sg;
  const u16* gB = Bt + (size_t)(n0 + rw) * K + kbase + sg;

  f32x4 acc[2][2] = {};
  const int nK = Kh >> 5;
  int cur = 0;

  GLOAD_LDS16(gA, &smem[rw * 32]);
  GLOAD_LDS16(gB, &smem[4096 + rw * 32]);
  __syncthreads();

  for (int kt = 0; kt < nK; ++kt) {
    if (kt + 1 < nK) {
      const int k0 = (kt + 1) << 5;
      GLOAD_LDS16(gA + k0, &smem[(cur ^ 1) * 2048 + rw * 32]);
      GLOAD_LDS16(gB + k0, &smem[4096 + (cur ^ 1) * 2048 + rw * 32]);
    }
    bf16x8 af[2], bfr[2];
#pragma unroll
    for (int i = 0; i < 2; ++i)
      af[i] = *(const bf16x8*)&smem[cur * 2048 + (wm * 32 + i * 16 + c) * 32 + g * 8];
#pragma unroll
    for (int j = 0; j < 2; ++j)
      bfr[j] = *(const bf16x8*)&smem[4096 + cur * 2048 + (wn * 32 + j * 16 + c) * 32 + g * 8];
#pragma unroll
    for (int i = 0; i < 2; ++i)
#pragma unroll
      for (int j = 0; j < 2; ++j)
        acc[i][j] = MFB(af[i], bfr[j], acc[i][j]);
    __syncthreads();
    cur ^= 1;
  }

#pragma unroll
  for (int i = 0; i < 2; ++i)
#pragma unroll
    for (int j = 0; j < 2; ++j)
#pragma unroll
      for (int r = 0; r < 4; ++r) {
        int m = m0 + wm * 32 + i * 16 + g * 4 + r;
        int n = n0 + wn * 32 + j * 16 + c;
        float v = acc[i][j][r] + (kz == 0 ? bias[n] : 0.f);
        atomAddF32(&fout[(size_t)m * N + n], v);
      }
}

// ---------------- GEMM 128x128 2-phase (LM head, f32+bias out), XCD swizzle ------
__launch_bounds__(256, 4)
__global__ void k_gemm_out(const u16* __restrict__ A, const u16* __restrict__ Bt,
                           const float* __restrict__ bias, float* __restrict__ fout,
                           int M, int N, int K) {
  __shared__ alignas(16) u16 sm[2][2][128][32];
  const int t = threadIdx.x;
  const int wave = t >> 6, lane = t & 63;
  const int wm = wave >> 1, wn = wave & 1;
  const int g = lane >> 4, c = lane & 15;
  // 4000 blocks = 8 XCDs x 500: bijective chunked swizzle; M fast within chunk
  const int wg = (blockIdx.x & 7) * 500 + (blockIdx.x >> 3);
  const int m0 = (wg & 15) * 128, n0 = (wg >> 4) * 128;

  const int srow = wave * 32 + (lane >> 2);
  const int sseg = (lane & 3) * 8;
  const u16* gA = A + (size_t)(m0 + srow) * K + sseg;
  const u16* gB = Bt + (size_t)(n0 + srow) * K + sseg;

  f32x4 acc[4][4] = {};
  const int nK = K >> 5;
  int cur = 0;

#pragma unroll
  for (int p = 0; p < 2; ++p) {
    GLOAD_LDS16(gA + (size_t)p * 16 * K, &sm[0][0][wave * 32 + p * 16][0]);
    GLOAD_LDS16(gB + (size_t)p * 16 * K, &sm[0][1][wave * 32 + p * 16][0]);
  }
  __syncthreads();

  for (int kt = 0; kt < nK; ++kt) {
    if (kt + 1 < nK) {
      const int k0 = (kt + 1) << 5;
#pragma unroll
      for (int p = 0; p < 2; ++p) {
        GLOAD_LDS16(gA + k0 + (size_t)p * 16 * K, &sm[cur ^ 1][0][wave * 32 + p * 16][0]);
        GLOAD_LDS16(gB + k0 + (size_t)p * 16 * K, &sm[cur ^ 1][1][wave * 32 + p * 16][0]);
      }
    }
    bf16x8 af[4], bfr[4];
#pragma unroll
    for (int i = 0; i < 4; ++i) {
      af[i]  = *(const bf16x8*)&sm[cur][0][wm * 64 + i * 16 + c][g * 8];
      bfr[i] = *(const bf16x8*)&sm[cur][1][wn * 64 + i * 16 + c][g * 8];
    }
#pragma unroll
    for (int i = 0; i < 4; ++i)
#pragma unroll
      for (int j = 0; j < 4; ++j)
        acc[i][j] = MFB(af[i], bfr[j], acc[i][j]);
    __syncthreads();
    cur ^= 1;
  }

  float (*st)[132] = (float(*)[132])sm;
#pragma unroll
  for (int i = 0; i < 4; ++i) {
#pragma unroll
    for (int j = 0; j < 4; ++j)
#pragma unroll
      for (int r = 0; r < 4; ++r)
        st[wm * 16 + g * 4 + r][wn * 64 + j * 16 + c] = acc[i][j][r];
    __syncthreads();
    {
      int row = t >> 3;
      int cs = (t & 7) * 16;
      int m = m0 + (row >> 4) * 64 + i * 16 + (row & 15);
      float* dst = fout + (size_t)m * N + n0 + cs;
#pragma unroll
      for (int q = 0; q < 4; ++q) {
        float4 v = *(const float4*)&st[row][cs + q * 4];
        float4 bb = *(const float4*)&bias[n0 + cs + q * 4];
        float4 o{v.x + bb.x, v.y + bb.y, v.z + bb.z, v.w + bb.w};
        *(float4*)(dst + q * 4) = o;
      }
    }
    __syncthreads();
  }
}

// ---------------- flash attention: K-split across 2 waves + merge ----------------
// Q pre-scaled by 1/8; mask only diagonal tile; per-lane deferred L-reduction.
#define AITER(ITV, MASKED)                                                    \
  {                                                                           \
    const int k0 = (ITV) << 5;                                                \
    bf16x8 kb0 = *(const bf16x8*)(Kh + (k0 + c) * 64 + g * 8);                \
    bf16x8 kb1 = *(const bf16x8*)(Kh + (k0 + c) * 64 + 32 + g * 8);           \
    bf16x8 kb2 = *(const bf16x8*)(Kh + (k0 + 16 + c) * 64 + g * 8);           \
    bf16x8 kb3 = *(const bf16x8*)(Kh + (k0 + 16 + c) * 64 + 32 + g * 8);      \
    bf16x8 bv0 = *(const bf16x8*)(VTh + (size_t)(c) * 1024 + k0 + g * 8);     \
    bf16x8 bv1 = *(const bf16x8*)(VTh + (size_t)(16 + c) * 1024 + k0 + g * 8);\
    bf16x8 bv2 = *(const bf16x8*)(VTh + (size_t)(32 + c) * 1024 + k0 + g * 8);\
    bf16x8 bv3 = *(const bf16x8*)(VTh + (size_t)(48 + c) * 1024 + k0 + g * 8);\
    f32x4 S[2][2];                                                            \
    __builtin_amdgcn_s_setprio(1);                                            \
    _Pragma("unroll") for (int qt = 0; qt < 2; ++qt) {                        \
      f32x4 z = {};                                                           \
      S[qt][0] = MFB(aq[qt][1], kb1, MFB(aq[qt][0], kb0, z));                 \
      S[qt][1] = MFB(aq[qt][1], kb3, MFB(aq[qt][0], kb2, z));                 \
    }                                                                         \
    __builtin_amdgcn_s_setprio(0);                                            \
    float sv[2][2][4], mt[2][4];                                              \
    float need = 0.0f;                                                        \
    _Pragma("unroll") for (int qt = 0; qt < 2; ++qt)                          \
      _Pragma("unroll") for (int r = 0; r < 4; ++r) {                         \
        float s0 = S[qt][0][r], s1 = S[qt][1][r];                             \
        if (MASKED) {                                                         \
          int q = q0 + qt * 16 + (g << 2) + r;                                \
          s0 = (k0 + c <= q) ? s0 : -1e30f;                                   \
          s1 = (k0 + 16 + c <= q) ? s1 : -1e30f;                              \
        }                                                                     \
        sv[qt][0][r] = s0; sv[qt][1][r] = s1;                                 \
        float m = fmaxf(s0, s1);                                              \
        m = fmaxf(m, __shfl_xor(m, 1));                                       \
        m = fmaxf(m, __shfl_xor(m, 2));                                       \
        m = fmaxf(m, __shfl_xor(m, 4));                                       \
        m = fmaxf(m, __shfl_xor(m, 8));                                       \
        mt[qt][r] = m;                                                        \
        need = fmaxf(need, m - Mr[qt][r]);                                    \
      }                                                                       \
    unsigned long long vote = __ballot(need <= 8.0f);                         \
    const bool nore = wv ? ((vote & 0xFFFFFFFF00000000ull) == 0xFFFFFFFF00000000ull) \
                         : ((vote & 0xFFFFFFFFull) == 0xFFFFFFFFull);         \
    _Pragma("unroll") for (int qt = 0; qt < 2; ++qt)                          \
      _Pragma("unroll") for (int r = 0; r < 4; ++r) {                         \
        float mn = nore ? Mr[qt][r] : fmaxf(Mr[qt][r], mt[qt][r]);            \
        float p0 = __expf(sv[qt][0][r] - mn);                                 \
        float p1 = __expf(sv[qt][1][r] - mn);                                 \
        if (nore) {                                                           \
          Lr[qt][r] += p0 + p1;       /* per-lane partial; reduced at end */  \
        } else {                                                              \
          float alpha = __expf(Mr[qt][r] - mn);                               \
          Lr[qt][r] = Lr[qt][r] * alpha + p0 + p1;                            \
          Mr[qt][r] = mn;                                                     \
          _Pragma("unroll") for (int nb = 0; nb < 4; ++nb) Oacc[qt][nb][r] *= alpha; \
        }                                                                     \
        Pl[wv][qt * 16 + (g << 2) + r][c] = f2bf(p0);                         \
        Pl[wv][qt * 16 + (g << 2) + r][16 + c] = f2bf(p1);                    \
      }                                                                       \
    __builtin_amdgcn_s_setprio(1);                                            \
    _Pragma("unroll") for (int qt = 0; qt < 2; ++qt) {                        \
      bf16x8 ap = *(const bf16x8*)&Pl[wv][qt * 16 + c][g * 8];                \
      Oacc[qt][0] = MFB(ap, bv0, Oacc[qt][0]);                                \
      Oacc[qt][1] = MFB(ap, bv1, Oacc[qt][1]);                                \
      Oacc[qt][2] = MFB(ap, bv2, Oacc[qt][2]);                                \
      Oacc[qt][3] = MFB(ap, bv3, Oacc[qt][3]);                                \
    }                                                                         \
    __builtin_amdgcn_s_setprio(0);                                            \
  }

__launch_bounds__(128)
__global__ void k_attn(const u16* __restrict__ Q, const u16* __restrict__ Kb,
                       const u16* __restrict__ VT, u16* __restrict__ O) {
  const int qb = 31 - blockIdx.x;  // heavy blocks dispatch first
  const int bh = blockIdx.y;       // 0..31
  const int tid = threadIdx.x;
  const int wv = tid >> 6;         // wave 0/1: lower/upper K half
  const int lane = tid & 63;
  const int g = lane >> 4, c = lane & 15;
  const int q0 = qb << 5;
  const u16* Qh = Q + (size_t)bh * 65536;
  const u16* Kh = Kb + (size_t)bh * 65536;
  const u16* VTh = VT + (size_t)bh * 65536;

  __shared__ u16 Pl[2][32][40];
  __shared__ float mrg[64][48];

  bf16x8 aq[2][2];
#pragma unroll
  for (int qt = 0; qt < 2; ++qt) {
    aq[qt][0] = *(const bf16x8*)(Qh + (q0 + qt * 16 + c) * 64 + g * 8);
    aq[qt][1] = *(const bf16x8*)(Qh + (q0 + qt * 16 + c) * 64 + 32 + g * 8);
  }

  f32x4 Oacc[2][4] = {};
  float Mr[2][4], Lr[2][4] = {};
#pragma unroll
  for (int qt = 0; qt < 2; ++qt)
#pragma unroll
    for (int r = 0; r < 4; ++r) Mr[qt][r] = -1e30f;

  const int nIt = qb + 1;
  const int half = (nIt + 1) >> 1;

  if (wv == 0) {
    if (qb == 0) {
      AITER(0, 1);
    } else {
      for (int it = 0; it < half; ++it) AITER(it, 0);   // all < qb: unmasked
    }
  } else {
    for (int it = half; it < nIt - 1; ++it) AITER(it, 0);
    if (qb >= 1) AITER(nIt - 1, 1);                      // diagonal tile
  }

  // merge: wave1 publishes partial state; wave0 combines, reduces L, writes out
  if (wv == 1) {
#pragma unroll
    for (int qt = 0; qt < 2; ++qt) {
#pragma unroll
      for (int nb = 0; nb < 4; ++nb)
#pragma unroll
        for (int r = 0; r < 4; ++r)
          mrg[lane][qt * 16 + nb * 4 + r] = Oacc[qt][nb][r];
#pragma unroll
      for (int r = 0; r < 4; ++r) {
        mrg[lane][32 + qt * 4 + r] = Mr[qt][r];
        mrg[lane][40 + qt * 4 + r] = Lr[qt][r];
      }
    }
  }
  __syncthreads();
  if (wv == 0) {
    const int b = bh >> 4, hh = bh & 15;
#pragma unroll
    for (int qt = 0; qt < 2; ++qt)
#pragma unroll
      for (int r = 0; r < 4; ++r) {
        float m1 = mrg[lane][32 + qt * 4 + r];
        float l1 = mrg[lane][40 + qt * 4 + r];
        float mm = fmaxf(Mr[qt][r], m1);
        float a0 = __expf(Mr[qt][r] - mm);
        float a1 = __expf(m1 - mm);
        float l = a0 * Lr[qt][r] + a1 * l1;   // per-lane partial
        l += __shfl_xor(l, 1);
        l += __shfl_xor(l, 2);
        l += __shfl_xor(l, 4);
        l += __shfl_xor(l, 8);
        float invl = 1.0f / l;
        int tt = q0 + qt * 16 + (g << 2) + r;
#pragma unroll
        for (int nb = 0; nb < 4; ++nb) {
          float o1 = mrg[lane][qt * 16 + nb * 4 + r];
          float val = (a0 * Oacc[qt][nb][r] + a1 * o1) * invl;
          int d = nb * 16 + c;
          O[((size_t)(b * 1024 + tt)) * 1024 + hh * 64 + d] = f2bf(val);
        }
      }
  }
}

// ---------------- launch ----------------
extern "C" void kernel_launch(void* const* d_in, const int* in_sizes, int n_in,
                              void* d_out, int out_size, void* d_ws, size_t ws_size,
                              hipStream_t stream) {
  const int*   idx  = (const int*)d_in[0];
  const float* tok  = (const float*)d_in[1];
  const float* pos  = (const float*)d_in[2];
  const float* Wq   = (const float*)d_in[3];
  const float* Wk   = (const float*)d_in[4];
  const float* Wv   = (const float*)d_in[5];
  const float* Wo   = (const float*)d_in[6];
  const float* bo   = (const float*)d_in[7];
  const float* ln1s = (const float*)d_in[8];
  const float* ln1b = (const float*)d_in[9];
  const float* ln2s = (const float*)d_in[10];
  const float* ln2b = (const float*)d_in[11];
  const float* W1   = (const float*)d_in[12];
  const float* b1   = (const float*)d_in[13];
  const float* W2   = (const float*)d_in[14];
  const float* b2   = (const float*)d_in[15];
  const float* lnfs = (const float*)d_in[16];
  const float* lnfb = (const float*)d_in[17];
  const float* Wlm  = (const float*)d_in[18];
  const float* blm  = (const float*)d_in[19];
  float* out = (float*)d_out;

  char* w = (char*)d_ws;
  auto alloc = [&](size_t bytes) {
    char* p = w;
    w += (bytes + 255) & ~(size_t)255;
    return p;
  };
  float* x  = (float*)alloc(2048ull * 1024 * 4);
  u16* h    = (u16*)alloc(2048ull * 1024 * 2);
  u16* qkv  = (u16*)alloc(3ull * 2097152 * 2);   // Q,K: [bh][t][64]; V: [bh][d][t]
  u16* o    = (u16*)alloc(2048ull * 1024 * 2);
  u16* a1   = (u16*)alloc(2048ull * 4096 * 2);
  u16* arena = (u16*)alloc(32000ull * 1024 * 2);

  dim3 b32(32, 32, 1);

  for (int l = 0; l < 4; ++l) {
    u16* qkvT = arena;
    u16* WoT  = arena + 3ull * 1048576;
    u16* W1T  = arena + 4ull * 1048576;
    u16* W2T  = arena + 8ull * 1048576;
    if (l == 0) {
      k_trans_embed_ln<<<12800, b32, 0, stream>>>(
          Wq, Wk, Wv, Wo, W1, W2, qkvT, WoT, W1T, W2T,
          idx, tok, pos, ln1s, ln1b, x, h);
    } else {
      k_trans_ln_layer<<<12800, b32, 0, stream>>>(
          Wq + (size_t)l * 1048576, Wk + (size_t)l * 1048576,
          Wv + (size_t)l * 1048576, Wo + (size_t)l * 1048576,
          W1 + (size_t)l * 4194304, W2 + (size_t)l * 4194304,
          qkvT, WoT, W1T, W2T,
          x, ln1s + l * 1024, ln1b + l * 1024, h);
    }

    k_gemm64<EPI_QKV><<<dim3(32, 24), 256, 0, stream>>>(h, qkvT, nullptr, qkv,
                                                        2048, 3072, 1024);
    k_attn<<<dim3(32, 32), 128, 0, stream>>>(qkv, qkv + 2097152, qkv + 2 * 2097152, o);
    k_gemm_res<<<dim3(32, 16, 2), 256, 0, stream>>>(o, WoT, bo + l * 1024, x,
                                                    2048, 1024, 1024);
    k_ln<<<2048, 256, 0, stream>>>(x, ln2s + l * 1024, ln2b + l * 1024, h);
    k_gemm64<EPI_RELU><<<dim3(32, 32), 256, 0, stream>>>(h, W1T, b1 + l * 4096, a1,
                                                         2048, 4096, 1024);
    k_gemm_res<<<dim3(32, 16, 2), 256, 0, stream>>>(a1, W2T, b2 + l * 1024, x,
                                                    2048, 1024, 4096);
  }

  k_lnf_transwlm<<<32512, b32, 0, stream>>>(Wlm, arena, x, lnfs, lnfb, h);
  k_gemm_out<<<4000, 256, 0, stream>>>(h, arena, blm, out, 2048, 32000, 1024);
}

// Round 15
// 1055.871 us; speedup vs baseline: 1.0752x; 1.0009x over previous
//
#include <hip/hip_runtime.h>

typedef unsigned short u16;
typedef unsigned int u32;
typedef __bf16 bf16x8 __attribute__((ext_vector_type(8)));
typedef float f32x4 __attribute__((ext_vector_type(4)));
typedef u16 u16x8 __attribute__((ext_vector_type(8)));
typedef u16 u16x4 __attribute__((ext_vector_type(4)));

static __device__ __forceinline__ u16 f2bf(float f) {
  u32 u = __builtin_bit_cast(u32, f);
  u32 r = (u + 0x7FFFu + ((u >> 16) & 1u)) >> 16;  // RNE; inputs finite
  return (u16)r;
}

static __device__ __forceinline__ void atomAddF32(float* p, float v) {
  asm volatile("global_atomic_add_f32 %0, %1, off" :: "v"(p), "v"(v) : "memory");
}

#define GLOAD_LDS16(gp, lp)                                                   \
  __builtin_amdgcn_global_load_lds(                                           \
      (const __attribute__((address_space(1))) void*)(gp),                    \
      (__attribute__((address_space(3))) void*)(lp), 16, 0, 0)

#define MFB(a, b, cc) __builtin_amdgcn_mfma_f32_16x16x32_bf16(a, b, cc, 0, 0, 0)

// ---- shared LN body for 1024-thread fused kernels: 4 rows/block ----
static __device__ __forceinline__ void ln4_body(
    int tid, int row, const float* __restrict__ xr,
    const float* __restrict__ sc, const float* __restrict__ bi,
    u16* __restrict__ out, float* red) {
  const int sub = tid >> 8, t = tid & 255;
  float4 v = *(const float4*)(xr + t * 4);
  float s = v.x + v.y + v.z + v.w;
  float ss = v.x * v.x + v.y * v.y + v.z * v.z + v.w * v.w;
  for (int d = 1; d < 64; d <<= 1) { s += __shfl_xor(s, d); ss += __shfl_xor(ss, d); }
  int wv = tid >> 6, lane = tid & 63;
  if (lane == 0) { red[wv * 2] = s; red[wv * 2 + 1] = ss; }
  __syncthreads();
  s = red[sub * 8] + red[sub * 8 + 2] + red[sub * 8 + 4] + red[sub * 8 + 6];
  ss = red[sub * 8 + 1] + red[sub * 8 + 3] + red[sub * 8 + 5] + red[sub * 8 + 7];
  float mu = s * (1.0f / 1024.0f);
  float var = ss * (1.0f / 1024.0f) - mu * mu;
  float inv = rsqrtf(var + 1e-5f);
  float4 g = *(const float4*)(sc + t * 4);
  float4 b = *(const float4*)(bi + t * 4);
  u16x4 o;
  o[0] = f2bf((v.x - mu) * inv * g.x + b.x);
  o[1] = f2bf((v.y - mu) * inv * g.y + b.y);
  o[2] = f2bf((v.z - mu) * inv * g.z + b.z);
  o[3] = f2bf((v.w - mu) * inv * g.w + b.w);
  *(u16x4*)(out + (size_t)row * 1024 + t * 4) = o;
}

// ---- shared per-layer weight-transpose block body (bid < 12288) ----
static __device__ __forceinline__ void transpose_layer_body(
    int bid, const float* Wq, const float* Wk, const float* Wv, const float* Wo,
    const float* W1, const float* W2, u16* qkvT, u16* WoT, u16* W1T, u16* W2T,
    float (*tile)[33]) {
  const float* src; u16* dst; int R, C, bx, by;
  if (bid < 4096) {
    int which = bid >> 10, tile_i = bid & 1023;
    bx = tile_i & 31; by = tile_i >> 5; R = 1024; C = 1024;
    src = which == 0 ? Wq : which == 1 ? Wk : which == 2 ? Wv : Wo;
    dst = which == 3 ? WoT : qkvT + (size_t)which * 1048576;
  } else if (bid < 8192) {
    int tile_i = bid - 4096; bx = tile_i & 127; by = tile_i >> 7; R = 1024; C = 4096;
    src = W1; dst = W1T;
  } else {
    int tile_i = bid - 8192; bx = tile_i & 31; by = tile_i >> 5; R = 4096; C = 1024;
    src = W2; dst = W2T;
  }
  int tx = threadIdx.x, ty = threadIdx.y;
  int c = bx * 32 + tx, r = by * 32 + ty;
  tile[ty][tx] = src[(size_t)r * C + c];
  __syncthreads();
  int dr = bx * 32 + ty, dc = by * 32 + tx;
  dst[(size_t)dr * R + dc] = f2bf(tile[tx][ty]);
}

// ---------------- fused: layer-0 weight transpose + embed + LN1 ----------------
__launch_bounds__(1024)
__global__ void k_trans_embed_ln(const float* __restrict__ Wq, const float* __restrict__ Wk,
                                 const float* __restrict__ Wv, const float* __restrict__ Wo,
                                 const float* __restrict__ W1, const float* __restrict__ W2,
                                 u16* __restrict__ qkvT, u16* __restrict__ WoT,
                                 u16* __restrict__ W1T, u16* __restrict__ W2T,
                                 const int* __restrict__ idx, const float* __restrict__ tok,
                                 const float* __restrict__ pos, const float* __restrict__ sc,
                                 const float* __restrict__ bi, float* __restrict__ x,
                                 u16* __restrict__ hout) {
  __shared__ float tile[32][33];
  __shared__ float red[32];
  int bid = blockIdx.x;
  if (bid < 12288) {
    transpose_layer_body(bid, Wq, Wk, Wv, Wo, W1, W2, qkvT, WoT, W1T, W2T, tile);
    return;
  }
  int tid = threadIdx.y * 32 + threadIdx.x;
  int sub = tid >> 8, t = tid & 255;
  int row = (bid - 12288) * 4 + sub;
  int tt = row & 1023;
  int id = idx[row];
  float4 a = *(const float4*)(tok + (size_t)id * 1024 + t * 4);
  float4 p = *(const float4*)(pos + (size_t)tt * 1024 + t * 4);
  float4 v{a.x + p.x, a.y + p.y, a.z + p.z, a.w + p.w};
  float* xr = x + (size_t)row * 1024;
  *(float4*)(xr + t * 4) = v;
  float s = v.x + v.y + v.z + v.w;
  float ss = v.x * v.x + v.y * v.y + v.z * v.z + v.w * v.w;
  for (int d = 1; d < 64; d <<= 1) { s += __shfl_xor(s, d); ss += __shfl_xor(ss, d); }
  int wv = tid >> 6, lane = tid & 63;
  if (lane == 0) { red[wv * 2] = s; red[wv * 2 + 1] = ss; }
  __syncthreads();
  s = red[sub * 8] + red[sub * 8 + 2] + red[sub * 8 + 4] + red[sub * 8 + 6];
  ss = red[sub * 8 + 1] + red[sub * 8 + 3] + red[sub * 8 + 5] + red[sub * 8 + 7];
  float mu = s * (1.0f / 1024.0f);
  float var = ss * (1.0f / 1024.0f) - mu * mu;
  float inv = rsqrtf(var + 1e-5f);
  float4 g = *(const float4*)(sc + t * 4);
  float4 b = *(const float4*)(bi + t * 4);
  u16x4 o;
  o[0] = f2bf((v.x - mu) * inv * g.x + b.x);
  o[1] = f2bf((v.y - mu) * inv * g.y + b.y);
  o[2] = f2bf((v.z - mu) * inv * g.z + b.z);
  o[3] = f2bf((v.w - mu) * inv * g.w + b.w);
  *(u16x4*)(hout + (size_t)row * 1024 + t * 4) = o;
}

// ---------------- fused: layer-l weight transpose + LN1 (l>0) ----------------
__launch_bounds__(1024)
__global__ void k_trans_ln_layer(const float* __restrict__ Wq, const float* __restrict__ Wk,
                                 const float* __restrict__ Wv, const float* __restrict__ Wo,
                                 const float* __restrict__ W1, const float* __restrict__ W2,
                                 u16* __restrict__ qkvT, u16* __restrict__ WoT,
                                 u16* __restrict__ W1T, u16* __restrict__ W2T,
                                 const float* __restrict__ x, const float* __restrict__ sc,
                                 const float* __restrict__ bi, u16* __restrict__ hout) {
  __shared__ float tile[32][33];
  __shared__ float red[32];
  int bid = blockIdx.x;
  if (bid < 12288) {
    transpose_layer_body(bid, Wq, Wk, Wv, Wo, W1, W2, qkvT, WoT, W1T, W2T, tile);
    return;
  }
  int tid = threadIdx.y * 32 + threadIdx.x;
  int row = (bid - 12288) * 4 + (tid >> 8);
  ln4_body(tid, row, x + (size_t)row * 1024, sc, bi, hout, red);
}

// ---------------- fused: final LN + Wlm transpose ----------------
__launch_bounds__(1024)
__global__ void k_lnf_transwlm(const float* __restrict__ Wlm, u16* __restrict__ dst,
                               const float* __restrict__ x, const float* __restrict__ sc,
                               const float* __restrict__ bi, u16* __restrict__ hout) {
  __shared__ float tile[32][33];
  __shared__ float red[32];
  int bid = blockIdx.x;
  if (bid < 32000) {
    int bx = bid % 1000, by = bid / 1000;
    int tx = threadIdx.x, ty = threadIdx.y;
    int c = bx * 32 + tx, r = by * 32 + ty;
    tile[ty][tx] = Wlm[(size_t)r * 32000 + c];
    __syncthreads();
    int dr = bx * 32 + ty, dc = by * 32 + tx;
    dst[(size_t)dr * 1024 + dc] = f2bf(tile[tx][ty]);
    return;
  }
  int tid = threadIdx.y * 32 + threadIdx.x;
  int row = (bid - 32000) * 4 + (tid >> 8);
  ln4_body(tid, row, x + (size_t)row * 1024, sc, bi, hout, red);
}

// ---------------- layernorm (f32 in) -> bf16 out (LN2, standalone) ----------------
__global__ void k_ln(const float* __restrict__ x, const float* __restrict__ sc,
                     const float* __restrict__ bi, u16* __restrict__ out) {
  int row = blockIdx.x;
  int t = threadIdx.x;
  const float* xr = x + (size_t)row * 1024;
  float4 v = *(const float4*)(xr + t * 4);
  float s = v.x + v.y + v.z + v.w;
  float ss = v.x * v.x + v.y * v.y + v.z * v.z + v.w * v.w;
  for (int d = 1; d < 64; d <<= 1) { s += __shfl_xor(s, d); ss += __shfl_xor(ss, d); }
  __shared__ float red[8];
  int wave = t >> 6, lane = t & 63;
  if (lane == 0) { red[wave] = s; red[wave + 4] = ss; }
  __syncthreads();
  s = red[0] + red[1] + red[2] + red[3];
  ss = red[4] + red[5] + red[6] + red[7];
  float mu = s * (1.0f / 1024.0f);
  float var = ss * (1.0f / 1024.0f) - mu * mu;
  float inv = rsqrtf(var + 1e-5f);
  float4 g = *(const float4*)(sc + t * 4);
  float4 b = *(const float4*)(bi + t * 4);
  u16x4 o;
  o[0] = f2bf((v.x - mu) * inv * g.x + b.x);
  o[1] = f2bf((v.y - mu) * inv * g.y + b.y);
  o[2] = f2bf((v.z - mu) * inv * g.z + b.z);
  o[3] = f2bf((v.w - mu) * inv * g.w + b.w);
  *(u16x4*)(out + (size_t)row * 1024 + t * 4) = o;
}

// ---------------- GEMMs: C[M][N] = A[M][K](bf16) x Bt[N][K](bf16)^T ----------------
enum { EPI_QKV = 0, EPI_RELU = 2 };

// 64x128 tile, 2-phase pipelined (QKV / RELU). 5 blocks/CU (reg check: ~88 <= 102).
template <int EPI>
__launch_bounds__(256, 5)
__global__ void k_gemm64(const u16* __restrict__ A, const u16* __restrict__ Bt,
                         const float* __restrict__ bias, u16* __restrict__ bout,
                         int M, int N, int K) {
  __shared__ alignas(16) u16 smem[12288];   // Al[2][64][32] | Bl[2][128][32]
#define AL(s, r, k) smem[(s)*2048 + (r)*32 + (k)]
#define BL(s, r, k) smem[4096 + (s)*4096 + (r)*32 + (k)]
  const int t = threadIdx.x;
  const int wave = t >> 6, lane = t & 63;
  const int wm = wave >> 1, wn = wave & 1;       // 2x2 waves: 32x64 out each
  const int g = lane >> 4, c = lane & 15;
  const int m0 = blockIdx.x * 64, n0 = blockIdx.y * 128;

  const int rwA = t >> 2, sgA = (t & 3) * 8;
  const u16* gA = A + (size_t)(m0 + rwA) * K + sgA;
  const u16* gB = Bt + (size_t)(n0 + rwA) * K + sgA;

  f32x4 acc[2][4] = {};
  const int nK = K >> 5;
  int cur = 0;

  GLOAD_LDS16(gA, &AL(0, rwA, 0));
#pragma unroll
  for (int p = 0; p < 2; ++p)
    GLOAD_LDS16(gB + (size_t)p * 64 * K, &BL(0, p * 64 + rwA, 0));
  __syncthreads();

  for (int kt = 0; kt < nK; ++kt) {
    if (kt + 1 < nK) {
      const int k0 = (kt + 1) << 5;
      GLOAD_LDS16(gA + k0, &AL(cur ^ 1, rwA, 0));
#pragma unroll
      for (int p = 0; p < 2; ++p)
        GLOAD_LDS16(gB + k0 + (size_t)p * 64 * K, &BL(cur ^ 1, p * 64 + rwA, 0));
    }
    bf16x8 af[2], bfr[4];
#pragma unroll
    for (int i = 0; i < 2; ++i)
      af[i] = *(const bf16x8*)&AL(cur, wm * 32 + i * 16 + c, g * 8);
#pragma unroll
    for (int j = 0; j < 4; ++j)
      bfr[j] = *(const bf16x8*)&BL(cur, wn * 64 + j * 16 + c, g * 8);
#pragma unroll
    for (int i = 0; i < 2; ++i)
#pragma unroll
      for (int j = 0; j < 4; ++j)
        acc[i][j] = MFB(af[i], bfr[j], acc[i][j]);
    __syncthreads();
    cur ^= 1;
  }

  if (EPI == EPI_QKV) {
    const int which = n0 >> 10;                  // 0=Q 1=K 2=V (uniform per block)
    const int b = m0 >> 10, t0 = m0 & 1023;
    const int hh0 = (n0 >> 6) & 15;
    if (which < 2) {
      const float qsc = (which == 0) ? 0.125f : 1.0f;   // pre-scale Q by 1/sqrt(HD)
      u16 (*Ct)[136] = (u16(*)[136])smem;
#pragma unroll
      for (int i = 0; i < 2; ++i)
#pragma unroll
        for (int j = 0; j < 4; ++j)
#pragma unroll
          for (int r = 0; r < 4; ++r)
            Ct[wm * 32 + i * 16 + g * 4 + r][wn * 64 + j * 16 + c] = f2bf(acc[i][j][r] * qsc);
      __syncthreads();
      u16* obase = bout + (size_t)which * 2097152;
#pragma unroll
      for (int itr = 0; itr < 4; ++itr) {
        int idx2 = itr * 256 + t;
        int s = idx2 >> 9;
        int tt = (idx2 >> 3) & 63;
        int seg = idx2 & 7;
        u16x8 vv = *(const u16x8*)&Ct[tt][s * 64 + seg * 8];
        *(u16x8*)(obase + ((size_t)(b * 16 + hh0 + s) * 1024 + (t0 + tt)) * 64 + seg * 8) = vv;
      }
    } else {
      // V transposed: stage [128 feat][72 tok], store [bh][d][t]
      u16 (*Cv)[72] = (u16(*)[72])smem;
#pragma unroll
      for (int i = 0; i < 2; ++i)
#pragma unroll
        for (int j = 0; j < 4; ++j) {
          u16x4 pk;
#pragma unroll
          for (int r = 0; r < 4; ++r) pk[r] = f2bf(acc[i][j][r]);
          *(u16x4*)&Cv[wn * 64 + j * 16 + c][wm * 32 + i * 16 + g * 4] = pk;
        }
      __syncthreads();
      u16* obase = bout + (size_t)2 * 2097152;
#pragma unroll
      for (int itr = 0; itr < 4; ++itr) {
        int idx2 = itr * 256 + t;
        int row = idx2 >> 3;
        int seg = idx2 & 7;
        int s = row >> 6, f = row & 63;
        u16x8 vv = *(const u16x8*)&Cv[row][seg * 8];
        *(u16x8*)(obase + ((size_t)(b * 16 + hh0 + s) * 64 + f) * 1024 + t0 + seg * 8) = vv;
      }
    }
  } else {  // EPI_RELU
    u16 (*Ct)[136] = (u16(*)[136])smem;
#pragma unroll
    for (int i = 0; i < 2; ++i)
#pragma unroll
      for (int j = 0; j < 4; ++j)
#pragma unroll
        for (int r = 0; r < 4; ++r) {
          float u = acc[i][j][r] + bias[n0 + wn * 64 + j * 16 + c];
          Ct[wm * 32 + i * 16 + g * 4 + r][wn * 64 + j * 16 + c] = f2bf(u > 0.f ? u : 0.f);
        }
    __syncthreads();
#pragma unroll
    for (int itr = 0; itr < 4; ++itr) {
      int idx2 = itr * 256 + t;
      int tt = idx2 >> 4, seg = idx2 & 15;
      *(u16x8*)(bout + (size_t)(m0 + tt) * N + n0 + seg * 8) =
          *(const u16x8*)&Ct[tt][seg * 8];
    }
  }
#undef AL
#undef BL
}

// 64x64 tile, 2-phase, SPLIT-K over gridDim.z; residual += via HW f32 atomics
__launch_bounds__(256, 8)
__global__ void k_gemm_res(const u16* __restrict__ A, const u16* __restrict__ Bt,
                           const float* __restrict__ bias, float* __restrict__ fout,
                           int M, int N, int K) {
  __shared__ alignas(16) u16 smem[8192];   // Al[2][64][32] | Bl[2][64][32]
  const int t = threadIdx.x;
  const int wave = t >> 6, lane = t & 63;
  const int wm = wave >> 1, wn = wave & 1;   // 2x2 waves: 32x32 out each
  const int g = lane >> 4, c = lane & 15;
  const int m0 = blockIdx.x * 64, n0 = blockIdx.y * 64;
  const int kz = blockIdx.z;
  const int Kh = K >> 1;                     // per-split K (z=2)
  const int kbase = kz * Kh;

  const int rw = t >> 2, sg = (t & 3) * 8;
  const u16* gA = A + (size_t)(m0 + rw) * K + kbase + sg;
  const u16* gB = Bt + (size_t)(n0 + rw) * K + kbase + sg;

  f32x4 acc[2][2] = {};
  const int nK = Kh >> 5;
  int cur = 0;

  GLOAD_LDS16(gA, &smem[rw * 32]);
  GLOAD_LDS16(gB, &smem[4096 + rw * 32]);
  __syncthreads();

  for (int kt = 0; kt < nK; ++kt) {
    if (kt + 1 < nK) {
      const int k0 = (kt + 1) << 5;
      GLOAD_LDS16(gA + k0, &smem[(cur ^ 1) * 2048 + rw * 32]);
      GLOAD_LDS16(gB + k0, &smem[4096 + (cur ^ 1) * 2048 + rw * 32]);
    }
    bf16x8 af[2], bfr[2];
#pragma unroll
    for (int i = 0; i < 2; ++i)
      af[i] = *(const bf16x8*)&smem[cur * 2048 + (wm * 32 + i * 16 + c) * 32 + g * 8];
#pragma unroll
    for (int j = 0; j < 2; ++j)
      bfr[j] = *(const bf16x8*)&smem[4096 + cur * 2048 + (wn * 32 + j * 16 + c) * 32 + g * 8];
#pragma unroll
    for (int i = 0; i < 2; ++i)
#pragma unroll
      for (int j = 0; j < 2; ++j)
        acc[i][j] = MFB(af[i], bfr[j], acc[i][j]);
    __syncthreads();
    cur ^= 1;
  }

#pragma unroll
  for (int i = 0; i < 2; ++i)
#pragma unroll
    for (int j = 0; j < 2; ++j)
#pragma unroll
      for (int r = 0; r < 4; ++r) {
        int m = m0 + wm * 32 + i * 16 + g * 4 + r;
        int n = n0 + wn * 32 + j * 16 + c;
        float v = acc[i][j][r] + (kz == 0 ? bias[n] : 0.f);
        atomAddF32(&fout[(size_t)m * N + n], v);
      }
}

// ---------------- GEMM 128x128 2-phase (LM head, f32+bias out), XCD swizzle ------
__launch_bounds__(256, 4)
__global__ void k_gemm_out(const u16* __restrict__ A, const u16* __restrict__ Bt,
                           const float* __restrict__ bias, float* __restrict__ fout,
                           int M, int N, int K) {
  __shared__ alignas(16) u16 sm[2][2][128][32];
  const int t = threadIdx.x;
  const int wave = t >> 6, lane = t & 63;
  const int wm = wave >> 1, wn = wave & 1;
  const int g = lane >> 4, c = lane & 15;
  const int wg = (blockIdx.x & 7) * 500 + (blockIdx.x >> 3);
  const int m0 = (wg & 15) * 128, n0 = (wg >> 4) * 128;

  const int srow = wave * 32 + (lane >> 2);
  const int sseg = (lane & 3) * 8;
  const u16* gA = A + (size_t)(m0 + srow) * K + sseg;
  const u16* gB = Bt + (size_t)(n0 + srow) * K + sseg;

  f32x4 acc[4][4] = {};
  const int nK = K >> 5;
  int cur = 0;

#pragma unroll
  for (int p = 0; p < 2; ++p) {
    GLOAD_LDS16(gA + (size_t)p * 16 * K, &sm[0][0][wave * 32 + p * 16][0]);
    GLOAD_LDS16(gB + (size_t)p * 16 * K, &sm[0][1][wave * 32 + p * 16][0]);
  }
  __syncthreads();

  for (int kt = 0; kt < nK; ++kt) {
    if (kt + 1 < nK) {
      const int k0 = (kt + 1) << 5;
#pragma unroll
      for (int p = 0; p < 2; ++p) {
        GLOAD_LDS16(gA + k0 + (size_t)p * 16 * K, &sm[cur ^ 1][0][wave * 32 + p * 16][0]);
        GLOAD_LDS16(gB + k0 + (size_t)p * 16 * K, &sm[cur ^ 1][1][wave * 32 + p * 16][0]);
      }
    }
    bf16x8 af[4], bfr[4];
#pragma unroll
    for (int i = 0; i < 4; ++i) {
      af[i]  = *(const bf16x8*)&sm[cur][0][wm * 64 + i * 16 + c][g * 8];
      bfr[i] = *(const bf16x8*)&sm[cur][1][wn * 64 + i * 16 + c][g * 8];
    }
#pragma unroll
    for (int i = 0; i < 4; ++i)
#pragma unroll
      for (int j = 0; j < 4; ++j)
        acc[i][j] = MFB(af[i], bfr[j], acc[i][j]);
    __syncthreads();
    cur ^= 1;
  }

  float (*st)[132] = (float(*)[132])sm;
#pragma unroll
  for (int i = 0; i < 4; ++i) {
#pragma unroll
    for (int j = 0; j < 4; ++j)
#pragma unroll
      for (int r = 0; r < 4; ++r)
        st[wm * 16 + g * 4 + r][wn * 64 + j * 16 + c] = acc[i][j][r];
    __syncthreads();
    {
      int row = t >> 3;
      int cs = (t & 7) * 16;
      int m = m0 + (row >> 4) * 64 + i * 16 + (row & 15);
      float* dst = fout + (size_t)m * N + n0 + cs;
#pragma unroll
      for (int q = 0; q < 4; ++q) {
        float4 v = *(const float4*)&st[row][cs + q * 4];
        float4 bb = *(const float4*)&bias[n0 + cs + q * 4];
        float4 o{v.x + bb.x, v.y + bb.y, v.z + bb.z, v.w + bb.w};
        *(float4*)(dst + q * 4) = o;
      }
    }
    __syncthreads();
  }
}

// ---------------- flash attention: K-split across 2 waves + merge ----------------
#define AITER(ITV, MASKED)                                                    \
  {                                                                           \
    const int k0 = (ITV) << 5;                                                \
    bf16x8 kb0 = *(const bf16x8*)(Kh + (k0 + c) * 64 + g * 8);                \
    bf16x8 kb1 = *(const bf16x8*)(Kh + (k0 + c) * 64 + 32 + g * 8);           \
    bf16x8 kb2 = *(const bf16x8*)(Kh + (k0 + 16 + c) * 64 + g * 8);           \
    bf16x8 kb3 = *(const bf16x8*)(Kh + (k0 + 16 + c) * 64 + 32 + g * 8);      \
    bf16x8 bv0 = *(const bf16x8*)(VTh + (size_t)(c) * 1024 + k0 + g * 8);     \
    bf16x8 bv1 = *(const bf16x8*)(VTh + (size_t)(16 + c) * 1024 + k0 + g * 8);\
    bf16x8 bv2 = *(const bf16x8*)(VTh + (size_t)(32 + c) * 1024 + k0 + g * 8);\
    bf16x8 bv3 = *(const bf16x8*)(VTh + (size_t)(48 + c) * 1024 + k0 + g * 8);\
    f32x4 S[2][2];                                                            \
    __builtin_amdgcn_s_setprio(1);                                            \
    _Pragma("unroll") for (int qt = 0; qt < 2; ++qt) {                        \
      f32x4 z = {};                                                           \
      S[qt][0] = MFB(aq[qt][1], kb1, MFB(aq[qt][0], kb0, z));                 \
      S[qt][1] = MFB(aq[qt][1], kb3, MFB(aq[qt][0], kb2, z));                 \
    }                                                                         \
    __builtin_amdgcn_s_setprio(0);                                            \
    float sv[2][2][4], mt[2][4];                                              \
    float need = 0.0f;                                                        \
    _Pragma("unroll") for (int qt = 0; qt < 2; ++qt)                          \
      _Pragma("unroll") for (int r = 0; r < 4; ++r) {                         \
        float s0 = S[qt][0][r], s1 = S[qt][1][r];                             \
        if (MASKED) {                                                         \
          int q = q0 + qt * 16 + (g << 2) + r;                                \
          s0 = (k0 + c <= q) ? s0 : -1e30f;                                   \
          s1 = (k0 + 16 + c <= q) ? s1 : -1e30f;                              \
        }                                                                     \
        sv[qt][0][r] = s0; sv[qt][1][r] = s1;                                 \
        float m = fmaxf(s0, s1);                                              \
        m = fmaxf(m, __shfl_xor(m, 1));                                       \
        m = fmaxf(m, __shfl_xor(m, 2));                                       \
        m = fmaxf(m, __shfl_xor(m, 4));                                       \
        m = fmaxf(m, __shfl_xor(m, 8));                                       \
        mt[qt][r] = m;                                                        \
        need = fmaxf(need, m - Mr[qt][r]);                                    \
      }                                                                       \
    unsigned long long vote = __ballot(need <= 8.0f);                         \
    const bool nore = wv ? ((vote & 0xFFFFFFFF00000000ull) == 0xFFFFFFFF00000000ull) \
                         : ((vote & 0xFFFFFFFFull) == 0xFFFFFFFFull);         \
    _Pragma("unroll") for (int qt = 0; qt < 2; ++qt)                          \
      _Pragma("unroll") for (int r = 0; r < 4; ++r) {                         \
        float mn = nore ? Mr[qt][r] : fmaxf(Mr[qt][r], mt[qt][r]);            \
        float p0 = __expf(sv[qt][0][r] - mn);                                 \
        float p1 = __expf(sv[qt][1][r] - mn);                                 \
        if (nore) {                                                           \
          Lr[qt][r] += p0 + p1;                                               \
        } else {                                                              \
          float alpha = __expf(Mr[qt][r] - mn);                               \
          Lr[qt][r] = Lr[qt][r] * alpha + p0 + p1;                            \
          Mr[qt][r] = mn;                                                     \
          _Pragma("unroll") for (int nb = 0; nb < 4; ++nb) Oacc[qt][nb][r] *= alpha; \
        }                                                                     \
        Pl[wv][qt * 16 + (g << 2) + r][c] = f2bf(p0);                         \
        Pl[wv][qt * 16 + (g << 2) + r][16 + c] = f2bf(p1);                    \
      }                                                                       \
    __builtin_amdgcn_s_setprio(1);                                            \
    _Pragma("unroll") for (int qt = 0; qt < 2; ++qt) {                        \
      bf16x8 ap = *(const bf16x8*)&Pl[wv][qt * 16 + c][g * 8];                \
      Oacc[qt][0] = MFB(ap, bv0, Oacc[qt][0]);                                \
      Oacc[qt][1] = MFB(ap, bv1, Oacc[qt][1]);                                \
      Oacc[qt][2] = MFB(ap, bv2, Oacc[qt][2]);                                \
      Oacc[qt][3] = MFB(ap, bv3, Oacc[qt][3]);                                \
    }                                                                         \
    __builtin_amdgcn_s_setprio(0);                                            \
  }

__launch_bounds__(128)
__global__ void k_attn(const u16* __restrict__ Q, const u16* __restrict__ Kb,
                       const u16* __restrict__ VT, u16* __restrict__ O) {
  const int qb = 31 - blockIdx.x;  // heavy blocks dispatch first
  const int bh = blockIdx.y;       // 0..31
  const int tid = threadIdx.x;
  const int wv = tid >> 6;         // wave 0/1: lower/upper K half
  const int lane = tid & 63;
  const int g = lane >> 4, c = lane & 15;
  const int q0 = qb << 5;
  const u16* Qh = Q + (size_t)bh * 65536;
  const u16* Kh = Kb + (size_t)bh * 65536;
  const u16* VTh = VT + (size_t)bh * 65536;

  __shared__ u16 Pl[2][32][40];
  __shared__ float mrg[64][48];

  bf16x8 aq[2][2];
#pragma unroll
  for (int qt = 0; qt < 2; ++qt) {
    aq[qt][0] = *(const bf16x8*)(Qh + (q0 + qt * 16 + c) * 64 + g * 8);
    aq[qt][1] = *(const bf16x8*)(Qh + (q0 + qt * 16 + c) * 64 + 32 + g * 8);
  }

  f32x4 Oacc[2][4] = {};
  float Mr[2][4], Lr[2][4] = {};
#pragma unroll
  for (int qt = 0; qt < 2; ++qt)
#pragma unroll
    for (int r = 0; r < 4; ++r) Mr[qt][r] = -1e30f;

  const int nIt = qb + 1;
  const int half = (nIt + 1) >> 1;

  if (wv == 0) {
    if (qb == 0) {
      AITER(0, 1);
    } else {
      for (int it = 0; it < half; ++it) AITER(it, 0);
    }
  } else {
    for (int it = half; it < nIt - 1; ++it) AITER(it, 0);
    if (qb >= 1) AITER(nIt - 1, 1);
  }

  if (wv == 1) {
#pragma unroll
    for (int qt = 0; qt < 2; ++qt) {
#pragma unroll
      for (int nb = 0; nb < 4; ++nb)
#pragma unroll
        for (int r = 0; r < 4; ++r)
          mrg[lane][qt * 16 + nb * 4 + r] = Oacc[qt][nb][r];
#pragma unroll
      for (int r = 0; r < 4; ++r) {
        mrg[lane][32 + qt * 4 + r] = Mr[qt][r];
        mrg[lane][40 + qt * 4 + r] = Lr[qt][r];
      }
    }
  }
  __syncthreads();
  if (wv == 0) {
    const int b = bh >> 4, hh = bh & 15;
#pragma unroll
    for (int qt = 0; qt < 2; ++qt)
#pragma unroll
      for (int r = 0; r < 4; ++r) {
        float m1 = mrg[lane][32 + qt * 4 + r];
        float l1 = mrg[lane][40 + qt * 4 + r];
        float mm = fmaxf(Mr[qt][r], m1);
        float a0 = __expf(Mr[qt][r] - mm);
        float a1 = __expf(m1 - mm);
        float l = a0 * Lr[qt][r] + a1 * l1;
        l += __shfl_xor(l, 1);
        l += __shfl_xor(l, 2);
        l += __shfl_xor(l, 4);
        l += __shfl_xor(l, 8);
        float invl = 1.0f / l;
        int tt = q0 + qt * 16 + (g << 2) + r;
#pragma unroll
        for (int nb = 0; nb < 4; ++nb) {
          float o1 = mrg[lane][qt * 16 + nb * 4 + r];
          float val = (a0 * Oacc[qt][nb][r] + a1 * o1) * invl;
          int d = nb * 16 + c;
          O[((size_t)(b * 1024 + tt)) * 1024 + hh * 64 + d] = f2bf(val);
        }
      }
  }
}

// ---------------- launch ----------------
extern "C" void kernel_launch(void* const* d_in, const int* in_sizes, int n_in,
                              void* d_out, int out_size, void* d_ws, size_t ws_size,
                              hipStream_t stream) {
  const int*   idx  = (const int*)d_in[0];
  const float* tok  = (const float*)d_in[1];
  const float* pos  = (const float*)d_in[2];
  const float* Wq   = (const float*)d_in[3];
  const float* Wk   = (const float*)d_in[4];
  const float* Wv   = (const float*)d_in[5];
  const float* Wo   = (const float*)d_in[6];
  const float* bo   = (const float*)d_in[7];
  const float* ln1s = (const float*)d_in[8];
  const float* ln1b = (const float*)d_in[9];
  const float* ln2s = (const float*)d_in[10];
  const float* ln2b = (const float*)d_in[11];
  const float* W1   = (const float*)d_in[12];
  const float* b1   = (const float*)d_in[13];
  const float* W2   = (const float*)d_in[14];
  const float* b2   = (const float*)d_in[15];
  const float* lnfs = (const float*)d_in[16];
  const float* lnfb = (const float*)d_in[17];
  const float* Wlm  = (const float*)d_in[18];
  const float* blm  = (const float*)d_in[19];
  float* out = (float*)d_out;

  char* w = (char*)d_ws;
  auto alloc = [&](size_t bytes) {
    char* p = w;
    w += (bytes + 255) & ~(size_t)255;
    return p;
  };
  float* x  = (float*)alloc(2048ull * 1024 * 4);
  u16* h    = (u16*)alloc(2048ull * 1024 * 2);
  u16* qkv  = (u16*)alloc(3ull * 2097152 * 2);   // Q,K: [bh][t][64]; V: [bh][d][t]
  u16* o    = (u16*)alloc(2048ull * 1024 * 2);
  u16* a1   = (u16*)alloc(2048ull * 4096 * 2);
  u16* arena = (u16*)alloc(32000ull * 1024 * 2);

  dim3 b32(32, 32, 1);

  for (int l = 0; l < 4; ++l) {
    u16* qkvT = arena;
    u16* WoT  = arena + 3ull * 1048576;
    u16* W1T  = arena + 4ull * 1048576;
    u16* W2T  = arena + 8ull * 1048576;
    if (l == 0) {
      k_trans_embed_ln<<<12800, b32, 0, stream>>>(
          Wq, Wk, Wv, Wo, W1, W2, qkvT, WoT, W1T, W2T,
          idx, tok, pos, ln1s, ln1b, x, h);
    } else {
      k_trans_ln_layer<<<12800, b32, 0, stream>>>(
          Wq + (size_t)l * 1048576, Wk + (size_t)l * 1048576,
          Wv + (size_t)l * 1048576, Wo + (size_t)l * 1048576,
          W1 + (size_t)l * 4194304, W2 + (size_t)l * 4194304,
          qkvT, WoT, W1T, W2T,
          x, ln1s + l * 1024, ln1b + l * 1024, h);
    }

    k_gemm64<EPI_QKV><<<dim3(32, 24), 256, 0, stream>>>(h, qkvT, nullptr, qkv,
                                                        2048, 3072, 1024);
    k_attn<<<dim3(32, 32), 128, 0, stream>>>(qkv, qkv + 2097152, qkv + 2 * 2097152, o);
    k_gemm_res<<<dim3(32, 16, 2), 256, 0, stream>>>(o, WoT, bo + l * 1024, x,
                                                    2048, 1024, 1024);
    k_ln<<<2048, 256, 0, stream>>>(x, ln2s + l * 1024, ln2b + l * 1024, h);
    k_gemm64<EPI_RELU><<<dim3(32, 32), 256, 0, stream>>>(h, W1T, b1 + l * 4096, a1,
                                                         2048, 4096, 1024);
    k_gemm_res<<<dim3(32, 16, 2), 256, 0, stream>>>(a1, W2T, b2 + l * 1024, x,
                                                    2048, 1024, 4096);
  }

  k_lnf_transwlm<<<32512, b32, 0, stream>>>(Wlm, arena, x, lnfs, lnfb, h);
  k_gemm_out<<<4000, 256, 0, stream>>>(h, arena, blm, out, 2048, 32000, 1024);
}